// Round 6
// baseline (314.958 us; speedup 1.0000x reference)
//
#include <hip/hip_runtime.h>
#include <math.h>

#define B_ 1024
#define S_ 128
#define H_ 1024
#define E_ 16
#define HID_ 1024
#define K_ 4
#define C_ 3
#define EPS_ 1e-5f

// prep kernel segment offsets (block ranges)
#define NB_MEAN 1024
#define NB_WD 256
#define NB_WE1 4096
#define NB_WC 4096
#define NB_RT 256
#define NB_BC 4
#define OFF_WD (NB_MEAN)
#define OFF_WE1 (OFF_WD + NB_WD)
#define OFF_WC (OFF_WE1 + NB_WE1)
#define OFF_RT (OFF_WC + NB_WC)
#define OFF_BC (OFF_RT + NB_RT)
#define NB_PREP (OFF_BC + NB_BC)

typedef __attribute__((ext_vector_type(8))) __bf16 bf16x8;
typedef __attribute__((ext_vector_type(4))) float f32x4;

__device__ __forceinline__ ushort bf16_rn(float f) {
  unsigned u = __float_as_uint(f);
  u += 0x7FFF + ((u >> 16) & 1);
  return (ushort)(u >> 16);
}
__device__ __forceinline__ float bf16_to_f(ushort h) {
  return __uint_as_float(((unsigned)h) << 16);
}
__device__ __forceinline__ void split2(float f, ushort& h, ushort& l) {
  h = bf16_rn(f);
  l = bf16_rn(f - bf16_to_f(h));
}
__device__ __forceinline__ void gload_lds16(const void* g, void* l) {
  __builtin_amdgcn_global_load_lds((const __attribute__((address_space(1))) void*)g,
                                   (__attribute__((address_space(3))) void*)l, 16, 0, 0);
}
__device__ __forceinline__ void waveRed3(float& s0, float& s1, float& s2) {
#pragma unroll
  for (int off = 32; off; off >>= 1) {
    s0 += __shfl_down(s0, off); s1 += __shfl_down(s1, off); s2 += __shfl_down(s2, off);
  }
}

// ---------------------------------------------------------------------------
// Phase A: prep mega-kernel (unchanged). Independent segments by block range.
// ---------------------------------------------------------------------------
__global__ __launch_bounds__(256) void prep_kernel(
    const float* __restrict__ hs,
    const float* __restrict__ Wd, const float* __restrict__ We1,
    const float* __restrict__ We2, const float* __restrict__ Wp, const float* __restrict__ bp,
    const float* __restrict__ Wr, const float* __restrict__ br,
    const float* __restrict__ be2,
    ushort* __restrict__ m_hi, ushort* __restrict__ m_lo,
    ushort* __restrict__ cls_hi, ushort* __restrict__ cls_lo,
    ushort* __restrict__ wd_hi, ushort* __restrict__ wd_lo,
    ushort* __restrict__ we1_hi, ushort* __restrict__ we1_lo,
    float* __restrict__ Wcomb, float* __restrict__ bcomb,
    int* __restrict__ topk_idx, float* __restrict__ topk_prob,
    int* __restrict__ counts, int* __restrict__ pairlist) {
  __shared__ float tbuf[64][65];
  const int blk = blockIdx.x;
  const int tid = threadIdx.x;

  if (blk < NB_MEAN) {
    // ---- mean over S + cls row, emit hi/lo bf16 splits ----
    int gid = blk * 256 + tid;
    int b = gid >> 8;
    int h4 = (gid & 255) << 2;
    const float* p = hs + (size_t)b * S_ * H_ + h4;
    float4 v0 = *(const float4*)p;
    float sx = v0.x, sy = v0.y, sz = v0.z, sw = v0.w;
#pragma unroll 8
    for (int s = 1; s < S_; ++s) {
      float4 v = *(const float4*)(p + (size_t)s * H_);
      sx += v.x; sy += v.y; sz += v.z; sw += v.w;
    }
    const float inv = 1.0f / (float)S_;
    float mv[4] = {sx * inv, sy * inv, sz * inv, sw * inv};
    float cv[4] = {v0.x, v0.y, v0.z, v0.w};
    ushort4 mh, ml, ch, cl;
    split2(mv[0], mh.x, ml.x); split2(mv[1], mh.y, ml.y); split2(mv[2], mh.z, ml.z); split2(mv[3], mh.w, ml.w);
    split2(cv[0], ch.x, cl.x); split2(cv[1], ch.y, cl.y); split2(cv[2], ch.z, cl.z); split2(cv[3], ch.w, cl.w);
    size_t o = (size_t)b * H_ + h4;
    *(ushort4*)&m_hi[o] = mh; *(ushort4*)&m_lo[o] = ml;
    *(ushort4*)&cls_hi[o] = ch; *(ushort4*)&cls_lo[o] = cl;
  } else if (blk < OFF_WC) {
    // ---- weight transpose + hi/lo split (Wd or one We1 expert) ----
    int t, zmat;
    const float* in;
    ushort *oh, *ol;
    if (blk < OFF_WE1) { t = blk - OFF_WD; zmat = 0; in = Wd; oh = wd_hi; ol = wd_lo; }
    else { int t2 = blk - OFF_WE1; zmat = t2 >> 8; t = t2 & 255; in = We1; oh = we1_hi; ol = we1_lo; }
    const int k0 = (t & 15) * 64, n0 = (t >> 4) * 64;
    const size_t mbase = (size_t)zmat * (1024 * 1024);
    const int c4 = (tid & 15) << 2;
    const int r0 = tid >> 4;
#pragma unroll
    for (int p = 0; p < 4; ++p) {
      int row = r0 + p * 16;
      float4 v = *(const float4*)&in[mbase + (size_t)(k0 + row) * 1024 + n0 + c4];
      tbuf[row][c4] = v.x; tbuf[row][c4 + 1] = v.y; tbuf[row][c4 + 2] = v.z; tbuf[row][c4 + 3] = v.w;
    }
    __syncthreads();
    const int k4 = (tid & 15) << 2;
#pragma unroll
    for (int p = 0; p < 4; ++p) {
      int n = r0 + p * 16;
      ushort4 hh, ll;
      split2(tbuf[k4 + 0][n], hh.x, ll.x);
      split2(tbuf[k4 + 1][n], hh.y, ll.y);
      split2(tbuf[k4 + 2][n], hh.z, ll.z);
      split2(tbuf[k4 + 3][n], hh.w, ll.w);
      size_t o = mbase + (size_t)(n0 + n) * 1024 + k0 + k4;
      *(ushort4*)&oh[o] = hh;
      *(ushort4*)&ol[o] = ll;
    }
  } else if (blk < OFF_RT) {
    // ---- Wcomb[e*HID+d,:] = We2[e,d,:] @ Wp ----
    const int row = (blk - OFF_WC) * 4 + (tid >> 6);
    const int lane = tid & 63;
    const float* wr = We2 + (size_t)row * HID_;
    float s0 = 0, s1 = 0, s2 = 0;
    for (int f = lane; f < HID_; f += 64) {
      float v = wr[f];
      s0 = fmaf(v, Wp[f * 3 + 0], s0);
      s1 = fmaf(v, Wp[f * 3 + 1], s1);
      s2 = fmaf(v, Wp[f * 3 + 2], s2);
    }
    waveRed3(s0, s1, s2);
    if (lane == 0) {
      Wcomb[row * 3 + 0] = s0; Wcomb[row * 3 + 1] = s1; Wcomb[row * 3 + 2] = s2;
    }
  } else if (blk < OFF_BC) {
    // ---- router: one wave per sample, 4 samples per block ----
    const int lane = tid & 63;
    const int b = (blk - OFF_RT) * 4 + (tid >> 6);
    const float* cls = hs + (size_t)b * S_ * H_;
    const int e = lane & 15, part = lane >> 4;
    float sum = 0.0f;
    for (int i = part * 256; i < part * 256 + 256; ++i)
      sum = fmaf(cls[i], Wr[i * E_ + e], sum);
    sum += __shfl_down(sum, 32);
    sum += __shfl_down(sum, 16);
    float lg[E_];
#pragma unroll
    for (int i = 0; i < E_; ++i) lg[i] = __shfl(sum, i);
    if (lane == 0) {
      for (int i = 0; i < E_; ++i) lg[i] += br[i];
      int idx[K_]; float tv[K_];
      for (int k = 0; k < K_; ++k) {
        int bi = 0; float bv = -1e30f;
        for (int i = 0; i < E_; ++i) { if (lg[i] > bv) { bv = lg[i]; bi = i; } }
        idx[k] = bi; tv[k] = bv; lg[bi] = -1e30f;
      }
      float mx = tv[0], ssum = 0.0f, p[K_];
      for (int k = 0; k < K_; ++k) { p[k] = expf(tv[k] - mx); ssum += p[k]; }
      for (int k = 0; k < K_; ++k) {
        p[k] /= ssum;
        topk_idx[b * K_ + k] = idx[k];
        topk_prob[b * K_ + k] = p[k];
        int pos = atomicAdd(&counts[idx[k]], 1);
        pairlist[idx[k] * B_ + pos] = b * K_ + k;
      }
    }
  } else {
    // ---- bcomb[e,:] = be2[e,:] @ Wp + bp ----
    const int e = (blk - OFF_BC) * 4 + (tid >> 6);
    const int lane = tid & 63;
    const float* wr = be2 + (size_t)e * HID_;
    float s0 = 0, s1 = 0, s2 = 0;
    for (int f = lane; f < HID_; f += 64) {
      float v = wr[f];
      s0 = fmaf(v, Wp[f * 3 + 0], s0);
      s1 = fmaf(v, Wp[f * 3 + 1], s1);
      s2 = fmaf(v, Wp[f * 3 + 2], s2);
    }
    waveRed3(s0, s1, s2);
    if (lane == 0) {
      bcomb[e * 3 + 0] = s0 + bp[0]; bcomb[e * 3 + 1] = s1 + bp[1]; bcomb[e * 3 + 2] = s2 + bp[2];
    }
  }
}

// ---------------------------------------------------------------------------
// Phase B: unified MFMA GEMM, 128x64 tile + SPLIT-K=2 for occupancy.
// blockIdx.y encodes (m-tile, k-half); blockIdx.x = n-tile (64-wide, 16 of
// them). Active blocks ~1280 (5/CU launched, ~4 co-resident: LDS 24 KB,
// ~116 VGPR) so per-iteration vmcnt(0)+barrier drains overlap across blocks.
// A-tile re-reads double vs BN=128 but m/cls hi+lo = 12 MB -> L2/L3 resident.
// Raw partials out (bias/tanh in epilogue). 4 waves = 2x2 over (64r x 32c).
// ---------------------------------------------------------------------------
__global__ __launch_bounds__(256) void gemm_mega(
    const ushort* __restrict__ m_hi, const ushort* __restrict__ m_lo,
    const ushort* __restrict__ cls_hi, const ushort* __restrict__ cls_lo,
    const ushort* __restrict__ wd_hi, const ushort* __restrict__ wd_lo,
    const ushort* __restrict__ we1_hi, const ushort* __restrict__ we1_lo,
    const int* __restrict__ counts, const int* __restrict__ pairlist,
    float* __restrict__ tA, float* __restrict__ tB,
    float* __restrict__ h1A, float* __restrict__ h1B) {
  __shared__ __align__(16) ushort ldsAh[4096], ldsAl[4096], ldsBh[2048], ldsBl[2048];
  const int z = blockIdx.z;
  const int tid = threadIdx.x;
  const int lane = tid & 63, w = tid >> 6;
  const int mt = blockIdx.y >> 1, kh = blockIdx.y & 1;
  const int m0 = mt * 128, n0 = blockIdx.x * 64;
  const int kbase = kh * 512;
  const int nsub = (w < 2) ? 8 : 4;   // A-waves stage 8 subtiles, B-waves 4
  const ushort* srcp[8];
  ushort* ldst = (w == 0) ? ldsAh : (w == 1) ? ldsAl : (w == 2) ? ldsBh : ldsBl;
  int n_e;
  if (z == 16) {
    n_e = B_;
    const ushort* sbase = (w == 0) ? cls_hi : (w == 1) ? cls_lo : (w == 2) ? wd_hi : wd_lo;
    const int base0 = (w < 2) ? m0 : n0;
    for (int s = 0; s < nsub; ++s) {
      int idx = base0 + s * 16 + (lane & 15);
      srcp[s] = sbase + (size_t)idx * H_ + ((lane >> 4) << 3);
    }
  } else {
    n_e = counts[z];
    if (m0 >= n_e) return;
    if (w < 2) {
      const ushort* sbase = (w == 0) ? m_hi : m_lo;
#pragma unroll
      for (int s = 0; s < 8; ++s) {
        int r = m0 + s * 16 + (lane & 15);
        if (r >= n_e) r = n_e - 1;
        int srow = pairlist[z * B_ + r] >> 2;
        srcp[s] = sbase + (size_t)srow * H_ + ((lane >> 4) << 3);
      }
    } else {
      const ushort* sbase = ((w == 2) ? we1_hi : we1_lo) + (size_t)z * H_ * HID_;
#pragma unroll
      for (int s = 0; s < 4; ++s) {
        int col = n0 + s * 16 + (lane & 15);
        srcp[s] = sbase + (size_t)col * H_ + ((lane >> 4) << 3);
      }
    }
  }
  const int wr = w >> 1, wc = w & 1;
  f32x4 acc[4][2] = {};
  for (int k0 = kbase; k0 < kbase + 512; k0 += 32) {
    for (int s = 0; s < nsub; ++s)
      gload_lds16(srcp[s] + k0, ldst + s * 512);
    __syncthreads();
    bf16x8 ah[4], al[4], bh[2], bl[2];
#pragma unroll
    for (int i = 0; i < 4; ++i) {
      int off = (wr * 4 + i) * 512 + lane * 8;
      ah[i] = *(const bf16x8*)&ldsAh[off];
      al[i] = *(const bf16x8*)&ldsAl[off];
    }
#pragma unroll
    for (int j = 0; j < 2; ++j) {
      int off = (wc * 2 + j) * 512 + lane * 8;
      bh[j] = *(const bf16x8*)&ldsBh[off];
      bl[j] = *(const bf16x8*)&ldsBl[off];
    }
#pragma unroll
    for (int i = 0; i < 4; ++i)
#pragma unroll
      for (int j = 0; j < 2; ++j) {
        acc[i][j] = __builtin_amdgcn_mfma_f32_16x16x32_bf16(ah[i], bh[j], acc[i][j], 0, 0, 0);
        acc[i][j] = __builtin_amdgcn_mfma_f32_16x16x32_bf16(ah[i], bl[j], acc[i][j], 0, 0, 0);
        acc[i][j] = __builtin_amdgcn_mfma_f32_16x16x32_bf16(al[i], bh[j], acc[i][j], 0, 0, 0);
      }
    __syncthreads();
  }
  const int lr = (lane >> 4) << 2, lc = lane & 15;
  if (z == 16) {
    float* tp = kh ? tB : tA;
#pragma unroll
    for (int i = 0; i < 4; ++i) {
      int row = m0 + wr * 64 + i * 16 + lr;
#pragma unroll
      for (int j = 0; j < 2; ++j) {
        int col = n0 + wc * 32 + j * 16 + lc;
#pragma unroll
        for (int r = 0; r < 4; ++r)
          tp[(size_t)(row + r) * H_ + col] = acc[i][j][r];
      }
    }
  } else {
    float* hp = kh ? h1B : h1A;
#pragma unroll
    for (int i = 0; i < 4; ++i) {
      int pr[4]; bool ok[4];
#pragma unroll
      for (int r = 0; r < 4; ++r) {
        int li = m0 + wr * 64 + i * 16 + lr + r;
        ok[r] = li < n_e;
        pr[r] = pairlist[z * B_ + (ok[r] ? li : n_e - 1)];
      }
#pragma unroll
      for (int j = 0; j < 2; ++j) {
        int col = n0 + wc * 32 + j * 16 + lc;
#pragma unroll
        for (int r = 0; r < 4; ++r)
          if (ok[r]) hp[(size_t)pr[r] * HID_ + col] = acc[i][j][r];
      }
    }
  }
}

// ---------------------------------------------------------------------------
// Phase C: fused epilogue (unchanged from R5). One block per sample b.
// ---------------------------------------------------------------------------
__global__ __launch_bounds__(256) void epi_kernel(
    const float* __restrict__ tA, const float* __restrict__ tB,
    const float* __restrict__ bd,
    const float* __restrict__ Wo, const float* __restrict__ bo,
    const float* __restrict__ h1A, const float* __restrict__ h1B,
    const float* __restrict__ be1,
    const float* __restrict__ g1, const float* __restrict__ beta1,
    const int* __restrict__ topk_idx, const float* __restrict__ topk_prob,
    const float* __restrict__ Wcomb, const float* __restrict__ bcomb,
    const float* __restrict__ Wf1, const float* __restrict__ bf1,
    const float* __restrict__ gf, const float* __restrict__ betaf,
    const float* __restrict__ Wf2, const float* __restrict__ bf2,
    float* __restrict__ out) {
  const int b = blockIdx.x;
  const int tid = threadIdx.x;
  const int w = tid >> 6, lane = tid & 63;
  __shared__ float sCtr[4][3];
  __shared__ float sOl[4][3];

  // ---- per-wave: expert pair LN + gelu + Wcomb dot ----
  const int pair = b * K_ + w;
  const int e = topk_idx[pair];
  const float prob = topk_prob[pair];
  const float* hrA = h1A + (size_t)pair * HID_;
  const float* hrB = h1B + (size_t)pair * HID_;
  const float* ber = be1 + (size_t)e * HID_;
  float4 x[4];
#pragma unroll
  for (int q = 0; q < 4; ++q) {
    const int d = q * 256 + lane * 4;
    float4 a = *(const float4*)&hrA[d];
    float4 bq = *(const float4*)&hrB[d];
    float4 be = *(const float4*)&ber[d];
    x[q].x = a.x + bq.x + be.x; x[q].y = a.y + bq.y + be.y;
    x[q].z = a.z + bq.z + be.z; x[q].w = a.w + bq.w + be.w;
  }
  float s = 0;
#pragma unroll
  for (int q = 0; q < 4; ++q) s += x[q].x + x[q].y + x[q].z + x[q].w;
#pragma unroll
  for (int off = 32; off; off >>= 1) s += __shfl_down(s, off);
  const float mu = __shfl(s, 0) * (1.0f / HID_);
  float sq = 0;
#pragma unroll
  for (int q = 0; q < 4; ++q) {
    float dx = x[q].x - mu, dy = x[q].y - mu, dz = x[q].z - mu, dw = x[q].w - mu;
    sq += dx * dx + dy * dy + dz * dz + dw * dw;
  }
#pragma unroll
  for (int off = 32; off; off >>= 1) sq += __shfl_down(sq, off);
  const float inv = 1.0f / sqrtf(__shfl(sq, 0) * (1.0f / HID_) + EPS_);
  float c0 = 0, c1 = 0, c2 = 0;
#pragma unroll
  for (int q = 0; q < 4; ++q) {
    const int d = q * 256 + lane * 4;
    float4 gg = *(const float4*)&g1[(size_t)e * HID_ + d];
    float4 bb = *(const float4*)&beta1[(size_t)e * HID_ + d];
    float xv[4] = {x[q].x, x[q].y, x[q].z, x[q].w};
    float gv[4] = {gg.x, gg.y, gg.z, gg.w};
    float bv[4] = {bb.x, bb.y, bb.z, bb.w};
#pragma unroll
    for (int i = 0; i < 4; ++i) {
      float v = (xv[i] - mu) * inv * gv[i] + bv[i];
      v = 0.5f * v * (1.0f + erff(v * 0.70710678118654752440f));  // exact gelu
      const float* wc = &Wcomb[(size_t)(e * HID_ + d + i) * 3];
      c0 = fmaf(v, wc[0], c0); c1 = fmaf(v, wc[1], c1); c2 = fmaf(v, wc[2], c2);
    }
  }
  waveRed3(c0, c1, c2);
  if (lane == 0) {
    sCtr[w][0] = prob * (c0 + bcomb[e * 3 + 0]);
    sCtr[w][1] = prob * (c1 + bcomb[e * 3 + 1]);
    sCtr[w][2] = prob * (c2 + bcomb[e * 3 + 2]);
  }

  // ---- per-wave: 256-chunk partial of ologits (tanh applied here) ----
  {
    const int h0 = w * 256 + lane * 4;
    float4 ta = *(const float4*)&tA[(size_t)b * H_ + h0];
    float4 tb = *(const float4*)&tB[(size_t)b * H_ + h0];
    float4 bdv = *(const float4*)&bd[h0];
    float tvv[4] = {tanhf(ta.x + tb.x + bdv.x), tanhf(ta.y + tb.y + bdv.y),
                    tanhf(ta.z + tb.z + bdv.z), tanhf(ta.w + tb.w + bdv.w)};
    float o0 = 0, o1 = 0, o2 = 0;
#pragma unroll
    for (int i = 0; i < 4; ++i) {
      const float* wo = &Wo[(size_t)(h0 + i) * 3];
      o0 = fmaf(tvv[i], wo[0], o0); o1 = fmaf(tvv[i], wo[1], o1); o2 = fmaf(tvv[i], wo[2], o2);
    }
    waveRed3(o0, o1, o2);
    if (lane == 0) { sOl[w][0] = o0; sOl[w][1] = o1; sOl[w][2] = o2; }
  }
  __syncthreads();

  // ---- thread 0: combine + final head ----
  if (tid == 0) {
    float comb[6];
#pragma unroll
    for (int c = 0; c < 3; ++c) {
      comb[c] = sOl[0][c] + sOl[1][c] + sOl[2][c] + sOl[3][c] + bo[c];
      comb[3 + c] = sCtr[0][c] + sCtr[1][c] + sCtr[2][c] + sCtr[3][c];
    }
    float z[3];
#pragma unroll
    for (int c = 0; c < 3; ++c) {
      float sv = bf1[c];
#pragma unroll
      for (int i = 0; i < 6; ++i) sv = fmaf(comb[i], Wf1[i * 3 + c], sv);
      z[c] = sv;
    }
    float mu3 = (z[0] + z[1] + z[2]) * (1.0f / 3.0f);
    float v0 = z[0] - mu3, v1 = z[1] - mu3, v2 = z[2] - mu3;
    float var = (v0 * v0 + v1 * v1 + v2 * v2) * (1.0f / 3.0f);
    float inv3 = 1.0f / sqrtf(var + EPS_);
    float r[3];
#pragma unroll
    for (int c = 0; c < 3; ++c) {
      float zz = (z[c] - mu3) * inv3 * gf[c] + betaf[c];
      r[c] = zz > 0.0f ? zz : 0.0f;
    }
#pragma unroll
    for (int c = 0; c < 3; ++c) {
      float sv = bf2[c];
#pragma unroll
      for (int i = 0; i < 3; ++i) sv = fmaf(r[i], Wf2[i * 3 + c], sv);
      out[b * 3 + c] = sv;
    }
  }
}

// ---------------------------------------------------------------------------
extern "C" void kernel_launch(void* const* d_in, const int* in_sizes, int n_in,
                              void* d_out, int out_size, void* d_ws, size_t ws_size,
                              hipStream_t stream) {
  const float* hs    = (const float*)d_in[0];
  const float* Wd    = (const float*)d_in[1];
  const float* bd    = (const float*)d_in[2];
  const float* Wo    = (const float*)d_in[3];
  const float* bo    = (const float*)d_in[4];
  const float* Wr    = (const float*)d_in[5];
  const float* br    = (const float*)d_in[6];
  const float* We1   = (const float*)d_in[7];
  const float* be1   = (const float*)d_in[8];
  const float* g1    = (const float*)d_in[9];
  const float* beta1 = (const float*)d_in[10];
  const float* We2   = (const float*)d_in[11];
  const float* be2   = (const float*)d_in[12];
  const float* Wp    = (const float*)d_in[13];
  const float* bp    = (const float*)d_in[14];
  const float* Wf1   = (const float*)d_in[15];
  const float* bf1   = (const float*)d_in[16];
  const float* gf    = (const float*)d_in[17];
  const float* betaf = (const float*)d_in[18];
  const float* Wf2   = (const float*)d_in[19];
  const float* bf2   = (const float*)d_in[20];
  float* out = (float*)d_out;

  char* w = (char*)d_ws;
  size_t off = 0;
  auto alloc = [&](size_t bytes) {
    void* p = w + off;
    off = (off + bytes + 255) & ~(size_t)255;
    return p;
  };
  ushort* m_hi   = (ushort*)alloc((size_t)B_ * H_ * 2);
  ushort* m_lo   = (ushort*)alloc((size_t)B_ * H_ * 2);
  ushort* cls_hi = (ushort*)alloc((size_t)B_ * H_ * 2);
  ushort* cls_lo = (ushort*)alloc((size_t)B_ * H_ * 2);
  ushort* wd_hi  = (ushort*)alloc((size_t)H_ * H_ * 2);
  ushort* wd_lo  = (ushort*)alloc((size_t)H_ * H_ * 2);
  ushort* we1_hi = (ushort*)alloc((size_t)E_ * H_ * HID_ * 2);
  ushort* we1_lo = (ushort*)alloc((size_t)E_ * H_ * HID_ * 2);
  float* ws_tA   = (float*)alloc((size_t)B_ * H_ * 4);
  float* ws_tB   = (float*)alloc((size_t)B_ * H_ * 4);
  float* ws_h1A  = (float*)alloc((size_t)B_ * K_ * HID_ * 4);
  float* ws_h1B  = (float*)alloc((size_t)B_ * K_ * HID_ * 4);
  float* ws_wc   = (float*)alloc((size_t)E_ * HID_ * 3 * 4);
  float* ws_bc   = (float*)alloc(E_ * 3 * 4);
  float* ws_prob = (float*)alloc(B_ * K_ * 4);
  int* ws_idx = (int*)alloc(B_ * K_ * 4);
  int* ws_cnt = (int*)alloc(E_ * 4);
  int* ws_pl  = (int*)alloc(E_ * B_ * 4);
  if (off > ws_size) return;

  hipMemsetAsync(ws_cnt, 0, E_ * sizeof(int), stream);

  prep_kernel<<<NB_PREP, 256, 0, stream>>>(hs, Wd, We1, We2, Wp, bp, Wr, br, be2,
                                           m_hi, m_lo, cls_hi, cls_lo, wd_hi, wd_lo,
                                           we1_hi, we1_lo, ws_wc, ws_bc,
                                           ws_idx, ws_prob, ws_cnt, ws_pl);
  gemm_mega<<<dim3(16, 16, 17), 256, 0, stream>>>(m_hi, m_lo, cls_hi, cls_lo,
                                                  wd_hi, wd_lo, we1_hi, we1_lo,
                                                  ws_cnt, ws_pl, ws_tA, ws_tB, ws_h1A, ws_h1B);
  epi_kernel<<<B_, 256, 0, stream>>>(ws_tA, ws_tB, bd, Wo, bo, ws_h1A, ws_h1B, be1,
                                     g1, beta1, ws_idx, ws_prob, ws_wc, ws_bc,
                                     Wf1, bf1, gf, betaf, Wf2, bf2, out);
}

// Round 8
// 290.666 us; speedup vs baseline: 1.0836x; 1.0836x over previous
//
#include <hip/hip_runtime.h>
#include <math.h>

#define B_ 1024
#define S_ 128
#define H_ 1024
#define E_ 16
#define HID_ 1024
#define K_ 4
#define C_ 3
#define EPS_ 1e-5f

// prep kernel segment offsets (block ranges)
#define NB_MEAN 1024
#define NB_WD 256
#define NB_WE1 4096
#define NB_WC 4096
#define NB_RT 256
#define NB_BC 4
#define OFF_WD (NB_MEAN)
#define OFF_WE1 (OFF_WD + NB_WD)
#define OFF_WC (OFF_WE1 + NB_WE1)
#define OFF_RT (OFF_WC + NB_WC)
#define OFF_BC (OFF_RT + NB_RT)
#define NB_PREP (OFF_BC + NB_BC)

typedef __attribute__((ext_vector_type(8))) __bf16 bf16x8;
typedef __attribute__((ext_vector_type(4))) float f32x4;
typedef __attribute__((ext_vector_type(4))) float fvec4;
typedef __attribute__((ext_vector_type(4))) unsigned short usvec4;

__device__ __forceinline__ ushort bf16_rn(float f) {
  unsigned u = __float_as_uint(f);
  u += 0x7FFF + ((u >> 16) & 1);
  return (ushort)(u >> 16);
}
__device__ __forceinline__ float bf16_to_f(ushort h) {
  return __uint_as_float(((unsigned)h) << 16);
}
__device__ __forceinline__ void split2(float f, ushort& h, ushort& l) {
  h = bf16_rn(f);
  l = bf16_rn(f - bf16_to_f(h));
}
__device__ __forceinline__ void gload_lds16(const void* g, void* l) {
  __builtin_amdgcn_global_load_lds((const __attribute__((address_space(1))) void*)g,
                                   (__attribute__((address_space(3))) void*)l, 16, 0, 0);
}
// nontemporal vector shims (builtin requires scalar/ext_vector pointers, not
// HIP_vector_type)
__device__ __forceinline__ fvec4 nt_load4f(const float* p) {
  return __builtin_nontemporal_load((const fvec4*)p);
}
__device__ __forceinline__ void nt_store4us(ushort* p, ushort a, ushort b, ushort c, ushort d) {
  usvec4 v; v.x = a; v.y = b; v.z = c; v.w = d;
  __builtin_nontemporal_store(v, (usvec4*)p);
}
__device__ __forceinline__ void nt_store1f(float* p, float v) {
  __builtin_nontemporal_store(v, p);
}
__device__ __forceinline__ void waveRed3(float& s0, float& s1, float& s2) {
#pragma unroll
  for (int off = 32; off; off >>= 1) {
    s0 += __shfl_down(s0, off); s1 += __shfl_down(s1, off); s2 += __shfl_down(s2, off);
  }
}

// ---------------------------------------------------------------------------
// Phase A: prep mega-kernel. Streams are nontemporal: the 512 MB hs read is
// touched once (L2 residency is pure pollution that evicts the weight splits
// the GEMM needs), and split outputs are consumed cross-XCD via L3 only.
// ---------------------------------------------------------------------------
__global__ __launch_bounds__(256) void prep_kernel(
    const float* __restrict__ hs,
    const float* __restrict__ Wd, const float* __restrict__ We1,
    const float* __restrict__ We2, const float* __restrict__ Wp, const float* __restrict__ bp,
    const float* __restrict__ Wr, const float* __restrict__ br,
    const float* __restrict__ be2,
    ushort* __restrict__ m_hi, ushort* __restrict__ m_lo,
    ushort* __restrict__ cls_hi, ushort* __restrict__ cls_lo,
    ushort* __restrict__ wd_hi, ushort* __restrict__ wd_lo,
    ushort* __restrict__ we1_hi, ushort* __restrict__ we1_lo,
    float* __restrict__ Wcomb, float* __restrict__ bcomb,
    int* __restrict__ topk_idx, float* __restrict__ topk_prob,
    int* __restrict__ counts, int* __restrict__ pairlist) {
  __shared__ float tbuf[64][65];
  const int blk = blockIdx.x;
  const int tid = threadIdx.x;

  if (blk < NB_MEAN) {
    // ---- mean over S + cls row, emit hi/lo bf16 splits (nt stream) ----
    int gid = blk * 256 + tid;
    int b = gid >> 8;
    int h4 = (gid & 255) << 2;
    const float* p = hs + (size_t)b * S_ * H_ + h4;
    fvec4 v0 = nt_load4f(p);
    float sx = v0.x, sy = v0.y, sz = v0.z, sw = v0.w;
#pragma unroll 8
    for (int s = 1; s < S_; ++s) {
      fvec4 v = nt_load4f(p + (size_t)s * H_);
      sx += v.x; sy += v.y; sz += v.z; sw += v.w;
    }
    const float inv = 1.0f / (float)S_;
    float mv[4] = {sx * inv, sy * inv, sz * inv, sw * inv};
    float cv[4] = {v0.x, v0.y, v0.z, v0.w};
    ushort mh[4], ml[4], ch[4], cl[4];
#pragma unroll
    for (int i = 0; i < 4; ++i) { split2(mv[i], mh[i], ml[i]); split2(cv[i], ch[i], cl[i]); }
    size_t o = (size_t)b * H_ + h4;
    nt_store4us(&m_hi[o], mh[0], mh[1], mh[2], mh[3]);
    nt_store4us(&m_lo[o], ml[0], ml[1], ml[2], ml[3]);
    nt_store4us(&cls_hi[o], ch[0], ch[1], ch[2], ch[3]);
    nt_store4us(&cls_lo[o], cl[0], cl[1], cl[2], cl[3]);
  } else if (blk < OFF_WC) {
    // ---- weight transpose + hi/lo split (Wd or one We1 expert) ----
    int t, zmat;
    const float* in;
    ushort *oh, *ol;
    if (blk < OFF_WE1) { t = blk - OFF_WD; zmat = 0; in = Wd; oh = wd_hi; ol = wd_lo; }
    else { int t2 = blk - OFF_WE1; zmat = t2 >> 8; t = t2 & 255; in = We1; oh = we1_hi; ol = we1_lo; }
    const int k0 = (t & 15) * 64, n0 = (t >> 4) * 64;
    const size_t mbase = (size_t)zmat * (1024 * 1024);
    const int c4 = (tid & 15) << 2;
    const int r0 = tid >> 4;
#pragma unroll
    for (int p = 0; p < 4; ++p) {
      int row = r0 + p * 16;
      fvec4 v = nt_load4f(&in[mbase + (size_t)(k0 + row) * 1024 + n0 + c4]);
      tbuf[row][c4] = v.x; tbuf[row][c4 + 1] = v.y; tbuf[row][c4 + 2] = v.z; tbuf[row][c4 + 3] = v.w;
    }
    __syncthreads();
    const int k4 = (tid & 15) << 2;
#pragma unroll
    for (int p = 0; p < 4; ++p) {
      int n = r0 + p * 16;
      ushort hh[4], ll[4];
#pragma unroll
      for (int i = 0; i < 4; ++i) split2(tbuf[k4 + i][n], hh[i], ll[i]);
      size_t o = mbase + (size_t)(n0 + n) * 1024 + k0 + k4;
      nt_store4us(&oh[o], hh[0], hh[1], hh[2], hh[3]);
      nt_store4us(&ol[o], ll[0], ll[1], ll[2], ll[3]);
    }
  } else if (blk < OFF_RT) {
    // ---- Wcomb[e*HID+d,:] = We2[e,d,:] @ Wp ----
    const int row = (blk - OFF_WC) * 4 + (tid >> 6);
    const int lane = tid & 63;
    const float* wr = We2 + (size_t)row * HID_;
    float s0 = 0, s1 = 0, s2 = 0;
    for (int f = lane; f < HID_; f += 64) {
      float v = wr[f];
      s0 = fmaf(v, Wp[f * 3 + 0], s0);
      s1 = fmaf(v, Wp[f * 3 + 1], s1);
      s2 = fmaf(v, Wp[f * 3 + 2], s2);
    }
    waveRed3(s0, s1, s2);
    if (lane == 0) {
      Wcomb[row * 3 + 0] = s0; Wcomb[row * 3 + 1] = s1; Wcomb[row * 3 + 2] = s2;
    }
  } else if (blk < OFF_BC) {
    // ---- router: one wave per sample, 4 samples per block ----
    const int lane = tid & 63;
    const int b = (blk - OFF_RT) * 4 + (tid >> 6);
    const float* cls = hs + (size_t)b * S_ * H_;
    const int e = lane & 15, part = lane >> 4;
    float sum = 0.0f;
    for (int i = part * 256; i < part * 256 + 256; ++i)
      sum = fmaf(cls[i], Wr[i * E_ + e], sum);
    sum += __shfl_down(sum, 32);
    sum += __shfl_down(sum, 16);
    float lg[E_];
#pragma unroll
    for (int i = 0; i < E_; ++i) lg[i] = __shfl(sum, i);
    if (lane == 0) {
      for (int i = 0; i < E_; ++i) lg[i] += br[i];
      int idx[K_]; float tv[K_];
      for (int k = 0; k < K_; ++k) {
        int bi = 0; float bv = -1e30f;
        for (int i = 0; i < E_; ++i) { if (lg[i] > bv) { bv = lg[i]; bi = i; } }
        idx[k] = bi; tv[k] = bv; lg[bi] = -1e30f;
      }
      float mx = tv[0], ssum = 0.0f, p[K_];
      for (int k = 0; k < K_; ++k) { p[k] = expf(tv[k] - mx); ssum += p[k]; }
      for (int k = 0; k < K_; ++k) {
        p[k] /= ssum;
        topk_idx[b * K_ + k] = idx[k];
        topk_prob[b * K_ + k] = p[k];
        int pos = atomicAdd(&counts[idx[k]], 1);
        pairlist[idx[k] * B_ + pos] = b * K_ + k;
      }
    }
  } else {
    // ---- bcomb[e,:] = be2[e,:] @ Wp + bp ----
    const int e = (blk - OFF_BC) * 4 + (tid >> 6);
    const int lane = tid & 63;
    const float* wr = be2 + (size_t)e * HID_;
    float s0 = 0, s1 = 0, s2 = 0;
    for (int f = lane; f < HID_; f += 64) {
      float v = wr[f];
      s0 = fmaf(v, Wp[f * 3 + 0], s0);
      s1 = fmaf(v, Wp[f * 3 + 1], s1);
      s2 = fmaf(v, Wp[f * 3 + 2], s2);
    }
    waveRed3(s0, s1, s2);
    if (lane == 0) {
      bcomb[e * 3 + 0] = s0 + bp[0]; bcomb[e * 3 + 1] = s1 + bp[1]; bcomb[e * 3 + 2] = s2 + bp[2];
    }
  }
}

// ---------------------------------------------------------------------------
// Phase B: unified MFMA GEMM, R5 config (128x128 tile, SPLIT-K=2, BK=32,
// 4 waves 2x2 of 64x64). Raw partials out via nontemporal stores (consumed
// once by epi, cross-XCD -> keep them out of L2 so B-panels stay resident).
// ---------------------------------------------------------------------------
__global__ __launch_bounds__(256) void gemm_mega(
    const ushort* __restrict__ m_hi, const ushort* __restrict__ m_lo,
    const ushort* __restrict__ cls_hi, const ushort* __restrict__ cls_lo,
    const ushort* __restrict__ wd_hi, const ushort* __restrict__ wd_lo,
    const ushort* __restrict__ we1_hi, const ushort* __restrict__ we1_lo,
    const int* __restrict__ counts, const int* __restrict__ pairlist,
    float* __restrict__ tA, float* __restrict__ tB,
    float* __restrict__ h1A, float* __restrict__ h1B) {
  __shared__ __align__(16) ushort ldsAh[4096], ldsAl[4096], ldsBh[4096], ldsBl[4096];
  const int z = blockIdx.z;
  const int tid = threadIdx.x;
  const int lane = tid & 63, w = tid >> 6;
  const int mt = blockIdx.y >> 1, kh = blockIdx.y & 1;
  const int m0 = mt * 128, n0 = blockIdx.x * 128;
  const int kbase = kh * 512;
  const ushort* srcp[8];
  ushort* ldst = (w == 0) ? ldsAh : (w == 1) ? ldsAl : (w == 2) ? ldsBh : ldsBl;
  int n_e;
  if (z == 16) {
    n_e = B_;
    const ushort* sbase = (w == 0) ? cls_hi : (w == 1) ? cls_lo : (w == 2) ? wd_hi : wd_lo;
    const int base0 = (w < 2) ? m0 : n0;
#pragma unroll
    for (int s = 0; s < 8; ++s) {
      int idx = base0 + s * 16 + (lane & 15);
      srcp[s] = sbase + (size_t)idx * H_ + ((lane >> 4) << 3);
    }
  } else {
    n_e = counts[z];
    if (m0 >= n_e) return;
    if (w < 2) {
      const ushort* sbase = (w == 0) ? m_hi : m_lo;
#pragma unroll
      for (int s = 0; s < 8; ++s) {
        int r = m0 + s * 16 + (lane & 15);
        if (r >= n_e) r = n_e - 1;
        int srow = pairlist[z * B_ + r] >> 2;
        srcp[s] = sbase + (size_t)srow * H_ + ((lane >> 4) << 3);
      }
    } else {
      const ushort* sbase = ((w == 2) ? we1_hi : we1_lo) + (size_t)z * H_ * HID_;
#pragma unroll
      for (int s = 0; s < 8; ++s) {
        int col = n0 + s * 16 + (lane & 15);
        srcp[s] = sbase + (size_t)col * H_ + ((lane >> 4) << 3);
      }
    }
  }
  const int wr = w >> 1, wc = w & 1;
  f32x4 acc[4][4] = {};
  for (int k0 = kbase; k0 < kbase + 512; k0 += 32) {
#pragma unroll
    for (int s = 0; s < 8; ++s)
      gload_lds16(srcp[s] + k0, ldst + s * 512);
    __syncthreads();
    bf16x8 ah[4], al[4], bh[4], bl[4];
#pragma unroll
    for (int i = 0; i < 4; ++i) {
      int off = (wr * 4 + i) * 512 + lane * 8;
      ah[i] = *(const bf16x8*)&ldsAh[off];
      al[i] = *(const bf16x8*)&ldsAl[off];
    }
#pragma unroll
    for (int j = 0; j < 4; ++j) {
      int off = (wc * 4 + j) * 512 + lane * 8;
      bh[j] = *(const bf16x8*)&ldsBh[off];
      bl[j] = *(const bf16x8*)&ldsBl[off];
    }
#pragma unroll
    for (int i = 0; i < 4; ++i)
#pragma unroll
      for (int j = 0; j < 4; ++j) {
        acc[i][j] = __builtin_amdgcn_mfma_f32_16x16x32_bf16(ah[i], bh[j], acc[i][j], 0, 0, 0);
        acc[i][j] = __builtin_amdgcn_mfma_f32_16x16x32_bf16(ah[i], bl[j], acc[i][j], 0, 0, 0);
        acc[i][j] = __builtin_amdgcn_mfma_f32_16x16x32_bf16(al[i], bh[j], acc[i][j], 0, 0, 0);
      }
    __syncthreads();
  }
  const int lr = (lane >> 4) << 2, lc = lane & 15;
  if (z == 16) {
    float* tp = kh ? tB : tA;
#pragma unroll
    for (int i = 0; i < 4; ++i) {
      int row = m0 + wr * 64 + i * 16 + lr;
#pragma unroll
      for (int j = 0; j < 4; ++j) {
        int col = n0 + wc * 64 + j * 16 + lc;
#pragma unroll
        for (int r = 0; r < 4; ++r)
          nt_store1f(&tp[(size_t)(row + r) * H_ + col], acc[i][j][r]);
      }
    }
  } else {
    float* hp = kh ? h1B : h1A;
#pragma unroll
    for (int i = 0; i < 4; ++i) {
      int pr[4]; bool ok[4];
#pragma unroll
      for (int r = 0; r < 4; ++r) {
        int li = m0 + wr * 64 + i * 16 + lr + r;
        ok[r] = li < n_e;
        pr[r] = pairlist[z * B_ + (ok[r] ? li : n_e - 1)];
      }
#pragma unroll
      for (int j = 0; j < 4; ++j) {
        int col = n0 + wc * 64 + j * 16 + lc;
#pragma unroll
        for (int r = 0; r < 4; ++r)
          if (ok[r]) nt_store1f(&hp[(size_t)pr[r] * HID_ + col], acc[i][j][r]);
      }
    }
  }
}

// ---------------------------------------------------------------------------
// Phase C: fused epilogue (unchanged). One block per sample b.
// ---------------------------------------------------------------------------
__global__ __launch_bounds__(256) void epi_kernel(
    const float* __restrict__ tA, const float* __restrict__ tB,
    const float* __restrict__ bd,
    const float* __restrict__ Wo, const float* __restrict__ bo,
    const float* __restrict__ h1A, const float* __restrict__ h1B,
    const float* __restrict__ be1,
    const float* __restrict__ g1, const float* __restrict__ beta1,
    const int* __restrict__ topk_idx, const float* __restrict__ topk_prob,
    const float* __restrict__ Wcomb, const float* __restrict__ bcomb,
    const float* __restrict__ Wf1, const float* __restrict__ bf1,
    const float* __restrict__ gf, const float* __restrict__ betaf,
    const float* __restrict__ Wf2, const float* __restrict__ bf2,
    float* __restrict__ out) {
  const int b = blockIdx.x;
  const int tid = threadIdx.x;
  const int w = tid >> 6, lane = tid & 63;
  __shared__ float sCtr[4][3];
  __shared__ float sOl[4][3];

  // ---- per-wave: expert pair LN + gelu + Wcomb dot ----
  const int pair = b * K_ + w;
  const int e = topk_idx[pair];
  const float prob = topk_prob[pair];
  const float* hrA = h1A + (size_t)pair * HID_;
  const float* hrB = h1B + (size_t)pair * HID_;
  const float* ber = be1 + (size_t)e * HID_;
  float x[4][4];
#pragma unroll
  for (int q = 0; q < 4; ++q) {
    const int d = q * 256 + lane * 4;
    fvec4 a = nt_load4f(&hrA[d]);
    fvec4 bq = nt_load4f(&hrB[d]);
    float4 be = *(const float4*)&ber[d];
    x[q][0] = a.x + bq.x + be.x; x[q][1] = a.y + bq.y + be.y;
    x[q][2] = a.z + bq.z + be.z; x[q][3] = a.w + bq.w + be.w;
  }
  float s = 0;
#pragma unroll
  for (int q = 0; q < 4; ++q) s += x[q][0] + x[q][1] + x[q][2] + x[q][3];
#pragma unroll
  for (int off = 32; off; off >>= 1) s += __shfl_down(s, off);
  const float mu = __shfl(s, 0) * (1.0f / HID_);
  float sq = 0;
#pragma unroll
  for (int q = 0; q < 4; ++q)
#pragma unroll
    for (int i = 0; i < 4; ++i) {
      float d = x[q][i] - mu;
      sq += d * d;
    }
#pragma unroll
  for (int off = 32; off; off >>= 1) sq += __shfl_down(sq, off);
  const float inv = 1.0f / sqrtf(__shfl(sq, 0) * (1.0f / HID_) + EPS_);
  float c0 = 0, c1 = 0, c2 = 0;
#pragma unroll
  for (int q = 0; q < 4; ++q) {
    const int d = q * 256 + lane * 4;
    float4 gg = *(const float4*)&g1[(size_t)e * HID_ + d];
    float4 bb = *(const float4*)&beta1[(size_t)e * HID_ + d];
    float gv[4] = {gg.x, gg.y, gg.z, gg.w};
    float bv[4] = {bb.x, bb.y, bb.z, bb.w};
#pragma unroll
    for (int i = 0; i < 4; ++i) {
      float v = (x[q][i] - mu) * inv * gv[i] + bv[i];
      v = 0.5f * v * (1.0f + erff(v * 0.70710678118654752440f));  // exact gelu
      const float* wc = &Wcomb[(size_t)(e * HID_ + d + i) * 3];
      c0 = fmaf(v, wc[0], c0); c1 = fmaf(v, wc[1], c1); c2 = fmaf(v, wc[2], c2);
    }
  }
  waveRed3(c0, c1, c2);
  if (lane == 0) {
    sCtr[w][0] = prob * (c0 + bcomb[e * 3 + 0]);
    sCtr[w][1] = prob * (c1 + bcomb[e * 3 + 1]);
    sCtr[w][2] = prob * (c2 + bcomb[e * 3 + 2]);
  }

  // ---- per-wave: 256-chunk partial of ologits (tanh applied here) ----
  {
    const int h0 = w * 256 + lane * 4;
    fvec4 ta = nt_load4f(&tA[(size_t)b * H_ + h0]);
    fvec4 tb = nt_load4f(&tB[(size_t)b * H_ + h0]);
    float4 bdv = *(const float4*)&bd[h0];
    float tvv[4] = {tanhf(ta.x + tb.x + bdv.x), tanhf(ta.y + tb.y + bdv.y),
                    tanhf(ta.z + tb.z + bdv.z), tanhf(ta.w + tb.w + bdv.w)};
    float o0 = 0, o1 = 0, o2 = 0;
#pragma unroll
    for (int i = 0; i < 4; ++i) {
      const float* wo = &Wo[(size_t)(h0 + i) * 3];
      o0 = fmaf(tvv[i], wo[0], o0); o1 = fmaf(tvv[i], wo[1], o1); o2 = fmaf(tvv[i], wo[2], o2);
    }
    waveRed3(o0, o1, o2);
    if (lane == 0) { sOl[w][0] = o0; sOl[w][1] = o1; sOl[w][2] = o2; }
  }
  __syncthreads();

  // ---- thread 0: combine + final head ----
  if (tid == 0) {
    float comb[6];
#pragma unroll
    for (int c = 0; c < 3; ++c) {
      comb[c] = sOl[0][c] + sOl[1][c] + sOl[2][c] + sOl[3][c] + bo[c];
      comb[3 + c] = sCtr[0][c] + sCtr[1][c] + sCtr[2][c] + sCtr[3][c];
    }
    float z[3];
#pragma unroll
    for (int c = 0; c < 3; ++c) {
      float sv = bf1[c];
#pragma unroll
      for (int i = 0; i < 6; ++i) sv = fmaf(comb[i], Wf1[i * 3 + c], sv);
      z[c] = sv;
    }
    float mu3 = (z[0] + z[1] + z[2]) * (1.0f / 3.0f);
    float v0 = z[0] - mu3, v1 = z[1] - mu3, v2 = z[2] - mu3;
    float var = (v0 * v0 + v1 * v1 + v2 * v2) * (1.0f / 3.0f);
    float inv3 = 1.0f / sqrtf(var + EPS_);
    float r[3];
#pragma unroll
    for (int c = 0; c < 3; ++c) {
      float zz = (z[c] - mu3) * inv3 * gf[c] + betaf[c];
      r[c] = zz > 0.0f ? zz : 0.0f;
    }
#pragma unroll
    for (int c = 0; c < 3; ++c) {
      float sv = bf2[c];
#pragma unroll
      for (int i = 0; i < 3; ++i) sv = fmaf(r[i], Wf2[i * 3 + c], sv);
      out[b * 3 + c] = sv;
    }
  }
}

// ---------------------------------------------------------------------------
extern "C" void kernel_launch(void* const* d_in, const int* in_sizes, int n_in,
                              void* d_out, int out_size, void* d_ws, size_t ws_size,
                              hipStream_t stream) {
  const float* hs    = (const float*)d_in[0];
  const float* Wd    = (const float*)d_in[1];
  const float* bd    = (const float*)d_in[2];
  const float* Wo    = (const float*)d_in[3];
  const float* bo    = (const float*)d_in[4];
  const float* Wr    = (const float*)d_in[5];
  const float* br    = (const float*)d_in[6];
  const float* We1   = (const float*)d_in[7];
  const float* be1   = (const float*)d_in[8];
  const float* g1    = (const float*)d_in[9];
  const float* beta1 = (const float*)d_in[10];
  const float* We2   = (const float*)d_in[11];
  const float* be2   = (const float*)d_in[12];
  const float* Wp    = (const float*)d_in[13];
  const float* bp    = (const float*)d_in[14];
  const float* Wf1   = (const float*)d_in[15];
  const float* bf1   = (const float*)d_in[16];
  const float* gf    = (const float*)d_in[17];
  const float* betaf = (const float*)d_in[18];
  const float* Wf2   = (const float*)d_in[19];
  const float* bf2   = (const float*)d_in[20];
  float* out = (float*)d_out;

  char* w = (char*)d_ws;
  size_t off = 0;
  auto alloc = [&](size_t bytes) {
    void* p = w + off;
    off = (off + bytes + 255) & ~(size_t)255;
    return p;
  };
  ushort* m_hi   = (ushort*)alloc((size_t)B_ * H_ * 2);
  ushort* m_lo   = (ushort*)alloc((size_t)B_ * H_ * 2);
  ushort* cls_hi = (ushort*)alloc((size_t)B_ * H_ * 2);
  ushort* cls_lo = (ushort*)alloc((size_t)B_ * H_ * 2);
  ushort* wd_hi  = (ushort*)alloc((size_t)H_ * H_ * 2);
  ushort* wd_lo  = (ushort*)alloc((size_t)H_ * H_ * 2);
  ushort* we1_hi = (ushort*)alloc((size_t)E_ * H_ * HID_ * 2);
  ushort* we1_lo = (ushort*)alloc((size_t)E_ * H_ * HID_ * 2);
  float* ws_tA   = (float*)alloc((size_t)B_ * H_ * 4);
  float* ws_tB   = (float*)alloc((size_t)B_ * H_ * 4);
  float* ws_h1A  = (float*)alloc((size_t)B_ * K_ * HID_ * 4);
  float* ws_h1B  = (float*)alloc((size_t)B_ * K_ * HID_ * 4);
  float* ws_wc   = (float*)alloc((size_t)E_ * HID_ * 3 * 4);
  float* ws_bc   = (float*)alloc(E_ * 3 * 4);
  float* ws_prob = (float*)alloc(B_ * K_ * 4);
  int* ws_idx = (int*)alloc(B_ * K_ * 4);
  int* ws_cnt = (int*)alloc(E_ * 4);
  int* ws_pl  = (int*)alloc(E_ * B_ * 4);
  if (off > ws_size) return;

  hipMemsetAsync(ws_cnt, 0, E_ * sizeof(int), stream);

  prep_kernel<<<NB_PREP, 256, 0, stream>>>(hs, Wd, We1, We2, Wp, bp, Wr, br, be2,
                                           m_hi, m_lo, cls_hi, cls_lo, wd_hi, wd_lo,
                                           we1_hi, we1_lo, ws_wc, ws_bc,
                                           ws_idx, ws_prob, ws_cnt, ws_pl);
  gemm_mega<<<dim3(8, 16, 17), 256, 0, stream>>>(m_hi, m_lo, cls_hi, cls_lo,
                                                 wd_hi, wd_lo, we1_hi, we1_lo,
                                                 ws_cnt, ws_pl, ws_tA, ws_tB, ws_h1A, ws_h1B);
  epi_kernel<<<B_, 256, 0, stream>>>(ws_tA, ws_tB, bd, Wo, bo, ws_h1A, ws_h1B, be1,
                                     g1, beta1, ws_idx, ws_prob, ws_wc, ws_bc,
                                     Wf1, bf1, gf, betaf, Wf2, bf2, out);
}

// Round 10
// 285.546 us; speedup vs baseline: 1.1030x; 1.0179x over previous
//
#include <hip/hip_runtime.h>
#include <math.h>

#define B_ 1024
#define S_ 128
#define H_ 1024
#define E_ 16
#define HID_ 1024
#define K_ 4
#define C_ 3
#define EPS_ 1e-5f

// prep kernel segment offsets (block ranges)
#define NB_MEAN 1024
#define NB_WD 256
#define NB_WE1 4096
#define NB_WC 4096
#define NB_RT 256
#define NB_BC 4
#define OFF_WD (NB_MEAN)
#define OFF_WE1 (OFF_WD + NB_WD)
#define OFF_WC (OFF_WE1 + NB_WE1)
#define OFF_RT (OFF_WC + NB_WC)
#define OFF_BC (OFF_RT + NB_RT)
#define NB_PREP (OFF_BC + NB_BC)

typedef __attribute__((ext_vector_type(8))) __bf16 bf16x8;
typedef __attribute__((ext_vector_type(4))) float f32x4;
typedef __attribute__((ext_vector_type(4))) float fvec4;
typedef __attribute__((ext_vector_type(4))) unsigned short usvec4;

__device__ __forceinline__ ushort bf16_rn(float f) {
  unsigned u = __float_as_uint(f);
  u += 0x7FFF + ((u >> 16) & 1);
  return (ushort)(u >> 16);
}
__device__ __forceinline__ float bf16_to_f(ushort h) {
  return __uint_as_float(((unsigned)h) << 16);
}
__device__ __forceinline__ void split2(float f, ushort& h, ushort& l) {
  h = bf16_rn(f);
  l = bf16_rn(f - bf16_to_f(h));
}
__device__ __forceinline__ void gload_lds16(const void* g, void* l) {
  __builtin_amdgcn_global_load_lds((const __attribute__((address_space(1))) void*)g,
                                   (__attribute__((address_space(3))) void*)l, 16, 0, 0);
}
// Explicit LDS-DMA drain: global_load_lds is tracked by vmcnt; make the drain
// unconditional (rule #18: asm waitcnt must be followed by sched_barrier(0)).
#define DMA_DRAIN() do {                                  \
    asm volatile("s_waitcnt vmcnt(0)" ::: "memory");      \
    __builtin_amdgcn_sched_barrier(0);                    \
  } while (0)

// nontemporal vector shims (builtin requires scalar/ext_vector pointers)
__device__ __forceinline__ fvec4 nt_load4f(const float* p) {
  return __builtin_nontemporal_load((const fvec4*)p);
}
__device__ __forceinline__ void nt_store4us(ushort* p, ushort a, ushort b, ushort c, ushort d) {
  usvec4 v; v.x = a; v.y = b; v.z = c; v.w = d;
  __builtin_nontemporal_store(v, (usvec4*)p);
}
__device__ __forceinline__ void nt_store1f(float* p, float v) {
  __builtin_nontemporal_store(v, p);
}
__device__ __forceinline__ void waveRed3(float& s0, float& s1, float& s2) {
#pragma unroll
  for (int off = 32; off; off >>= 1) {
    s0 += __shfl_down(s0, off); s1 += __shfl_down(s1, off); s2 += __shfl_down(s2, off);
  }
}

// ---------------------------------------------------------------------------
// Phase A: prep mega-kernel (unchanged from R8). Nontemporal streams.
// ---------------------------------------------------------------------------
__global__ __launch_bounds__(256) void prep_kernel(
    const float* __restrict__ hs,
    const float* __restrict__ Wd, const float* __restrict__ We1,
    const float* __restrict__ We2, const float* __restrict__ Wp, const float* __restrict__ bp,
    const float* __restrict__ Wr, const float* __restrict__ br,
    const float* __restrict__ be2,
    ushort* __restrict__ m_hi, ushort* __restrict__ m_lo,
    ushort* __restrict__ cls_hi, ushort* __restrict__ cls_lo,
    ushort* __restrict__ wd_hi, ushort* __restrict__ wd_lo,
    ushort* __restrict__ we1_hi, ushort* __restrict__ we1_lo,
    float* __restrict__ Wcomb, float* __restrict__ bcomb,
    int* __restrict__ topk_idx, float* __restrict__ topk_prob,
    int* __restrict__ counts, int* __restrict__ pairlist) {
  __shared__ float tbuf[64][65];
  const int blk = blockIdx.x;
  const int tid = threadIdx.x;

  if (blk < NB_MEAN) {
    int gid = blk * 256 + tid;
    int b = gid >> 8;
    int h4 = (gid & 255) << 2;
    const float* p = hs + (size_t)b * S_ * H_ + h4;
    fvec4 v0 = nt_load4f(p);
    float sx = v0.x, sy = v0.y, sz = v0.z, sw = v0.w;
#pragma unroll 8
    for (int s = 1; s < S_; ++s) {
      fvec4 v = nt_load4f(p + (size_t)s * H_);
      sx += v.x; sy += v.y; sz += v.z; sw += v.w;
    }
    const float inv = 1.0f / (float)S_;
    float mv[4] = {sx * inv, sy * inv, sz * inv, sw * inv};
    float cv[4] = {v0.x, v0.y, v0.z, v0.w};
    ushort mh[4], ml[4], ch[4], cl[4];
#pragma unroll
    for (int i = 0; i < 4; ++i) { split2(mv[i], mh[i], ml[i]); split2(cv[i], ch[i], cl[i]); }
    size_t o = (size_t)b * H_ + h4;
    nt_store4us(&m_hi[o], mh[0], mh[1], mh[2], mh[3]);
    nt_store4us(&m_lo[o], ml[0], ml[1], ml[2], ml[3]);
    nt_store4us(&cls_hi[o], ch[0], ch[1], ch[2], ch[3]);
    nt_store4us(&cls_lo[o], cl[0], cl[1], cl[2], cl[3]);
  } else if (blk < OFF_WC) {
    int t, zmat;
    const float* in;
    ushort *oh, *ol;
    if (blk < OFF_WE1) { t = blk - OFF_WD; zmat = 0; in = Wd; oh = wd_hi; ol = wd_lo; }
    else { int t2 = blk - OFF_WE1; zmat = t2 >> 8; t = t2 & 255; in = We1; oh = we1_hi; ol = we1_lo; }
    const int k0 = (t & 15) * 64, n0 = (t >> 4) * 64;
    const size_t mbase = (size_t)zmat * (1024 * 1024);
    const int c4 = (tid & 15) << 2;
    const int r0 = tid >> 4;
#pragma unroll
    for (int p = 0; p < 4; ++p) {
      int row = r0 + p * 16;
      fvec4 v = nt_load4f(&in[mbase + (size_t)(k0 + row) * 1024 + n0 + c4]);
      tbuf[row][c4] = v.x; tbuf[row][c4 + 1] = v.y; tbuf[row][c4 + 2] = v.z; tbuf[row][c4 + 3] = v.w;
    }
    __syncthreads();
    const int k4 = (tid & 15) << 2;
#pragma unroll
    for (int p = 0; p < 4; ++p) {
      int n = r0 + p * 16;
      ushort hh[4], ll[4];
#pragma unroll
      for (int i = 0; i < 4; ++i) split2(tbuf[k4 + i][n], hh[i], ll[i]);
      size_t o = mbase + (size_t)(n0 + n) * 1024 + k0 + k4;
      nt_store4us(&oh[o], hh[0], hh[1], hh[2], hh[3]);
      nt_store4us(&ol[o], ll[0], ll[1], ll[2], ll[3]);
    }
  } else if (blk < OFF_RT) {
    const int row = (blk - OFF_WC) * 4 + (tid >> 6);
    const int lane = tid & 63;
    const float* wr = We2 + (size_t)row * HID_;
    float s0 = 0, s1 = 0, s2 = 0;
    for (int f = lane; f < HID_; f += 64) {
      float v = wr[f];
      s0 = fmaf(v, Wp[f * 3 + 0], s0);
      s1 = fmaf(v, Wp[f * 3 + 1], s1);
      s2 = fmaf(v, Wp[f * 3 + 2], s2);
    }
    waveRed3(s0, s1, s2);
    if (lane == 0) {
      Wcomb[row * 3 + 0] = s0; Wcomb[row * 3 + 1] = s1; Wcomb[row * 3 + 2] = s2;
    }
  } else if (blk < OFF_BC) {
    const int lane = tid & 63;
    const int b = (blk - OFF_RT) * 4 + (tid >> 6);
    const float* cls = hs + (size_t)b * S_ * H_;
    const int e = lane & 15, part = lane >> 4;
    float sum = 0.0f;
    for (int i = part * 256; i < part * 256 + 256; ++i)
      sum = fmaf(cls[i], Wr[i * E_ + e], sum);
    sum += __shfl_down(sum, 32);
    sum += __shfl_down(sum, 16);
    float lg[E_];
#pragma unroll
    for (int i = 0; i < E_; ++i) lg[i] = __shfl(sum, i);
    if (lane == 0) {
      for (int i = 0; i < E_; ++i) lg[i] += br[i];
      int idx[K_]; float tv[K_];
      for (int k = 0; k < K_; ++k) {
        int bi = 0; float bv = -1e30f;
        for (int i = 0; i < E_; ++i) { if (lg[i] > bv) { bv = lg[i]; bi = i; } }
        idx[k] = bi; tv[k] = bv; lg[bi] = -1e30f;
      }
      float mx = tv[0], ssum = 0.0f, p[K_];
      for (int k = 0; k < K_; ++k) { p[k] = expf(tv[k] - mx); ssum += p[k]; }
      for (int k = 0; k < K_; ++k) {
        p[k] /= ssum;
        topk_idx[b * K_ + k] = idx[k];
        topk_prob[b * K_ + k] = p[k];
        int pos = atomicAdd(&counts[idx[k]], 1);
        pairlist[idx[k] * B_ + pos] = b * K_ + k;
      }
    }
  } else {
    const int e = (blk - OFF_BC) * 4 + (tid >> 6);
    const int lane = tid & 63;
    const float* wr = be2 + (size_t)e * HID_;
    float s0 = 0, s1 = 0, s2 = 0;
    for (int f = lane; f < HID_; f += 64) {
      float v = wr[f];
      s0 = fmaf(v, Wp[f * 3 + 0], s0);
      s1 = fmaf(v, Wp[f * 3 + 1], s1);
      s2 = fmaf(v, Wp[f * 3 + 2], s2);
    }
    waveRed3(s0, s1, s2);
    if (lane == 0) {
      bcomb[e * 3 + 0] = s0 + bp[0]; bcomb[e * 3 + 1] = s1 + bp[1]; bcomb[e * 3 + 2] = s2 + bp[2];
    }
  }
}

// ---------------------------------------------------------------------------
// Phase B: unified MFMA GEMM, 128x128 tile, SPLIT-K=2, BK=32, 2-phase LDS
// double-buffer — RACE-FIXED version of R9:
//   * t-loop unrolled 2x with STATICALLY-NAMED buffers (no runtime-indexed
//     buffer pair; rule #20 — also gives the waitcnt inserter exact LDS-DMA
//     target info)
//   * explicit `s_waitcnt vmcnt(0)` + sched_barrier(0) before every
//     __syncthreads() (rule #18) — the LDS-DMA drain is unconditional, not
//     dependent on the compiler's barrier lowering.
// One barrier per K-step; staging of tile t+1 is issued before the ds_read+
// MFMA of tile t so its latency hides under compute.
// ---------------------------------------------------------------------------
__global__ __launch_bounds__(256) void gemm_mega(
    const ushort* __restrict__ m_hi, const ushort* __restrict__ m_lo,
    const ushort* __restrict__ cls_hi, const ushort* __restrict__ cls_lo,
    const ushort* __restrict__ wd_hi, const ushort* __restrict__ wd_lo,
    const ushort* __restrict__ we1_hi, const ushort* __restrict__ we1_lo,
    const int* __restrict__ counts, const int* __restrict__ pairlist,
    float* __restrict__ tA, float* __restrict__ tB,
    float* __restrict__ h1A, float* __restrict__ h1B) {
  __shared__ __align__(16) ushort ldsAh0[4096], ldsAl0[4096], ldsBh0[4096], ldsBl0[4096];
  __shared__ __align__(16) ushort ldsAh1[4096], ldsAl1[4096], ldsBh1[4096], ldsBl1[4096];
  const int z = blockIdx.z;
  const int tid = threadIdx.x;
  const int lane = tid & 63, w = tid >> 6;
  const int mt = blockIdx.y >> 1, kh = blockIdx.y & 1;
  const int m0 = mt * 128, n0 = blockIdx.x * 128;
  const int kbase = kh * 512;
  const ushort* srcp[8];
  ushort* dst0 = (w == 0) ? ldsAh0 : (w == 1) ? ldsAl0 : (w == 2) ? ldsBh0 : ldsBl0;
  ushort* dst1 = (w == 0) ? ldsAh1 : (w == 1) ? ldsAl1 : (w == 2) ? ldsBh1 : ldsBl1;
  int n_e;
  if (z == 16) {
    n_e = B_;
    const ushort* sbase = (w == 0) ? cls_hi : (w == 1) ? cls_lo : (w == 2) ? wd_hi : wd_lo;
    const int base0 = (w < 2) ? m0 : n0;
#pragma unroll
    for (int s = 0; s < 8; ++s) {
      int idx = base0 + s * 16 + (lane & 15);
      srcp[s] = sbase + (size_t)idx * H_ + ((lane >> 4) << 3);
    }
  } else {
    n_e = counts[z];
    if (m0 >= n_e) return;
    if (w < 2) {
      const ushort* sbase = (w == 0) ? m_hi : m_lo;
#pragma unroll
      for (int s = 0; s < 8; ++s) {
        int r = m0 + s * 16 + (lane & 15);
        if (r >= n_e) r = n_e - 1;
        int srow = pairlist[z * B_ + r] >> 2;
        srcp[s] = sbase + (size_t)srow * H_ + ((lane >> 4) << 3);
      }
    } else {
      const ushort* sbase = ((w == 2) ? we1_hi : we1_lo) + (size_t)z * H_ * HID_;
#pragma unroll
      for (int s = 0; s < 8; ++s) {
        int col = n0 + s * 16 + (lane & 15);
        srcp[s] = sbase + (size_t)col * H_ + ((lane >> 4) << 3);
      }
    }
  }
  const int wr = w >> 1, wc = w & 1;
  f32x4 acc[4][4] = {};

  auto stage = [&](int kofs, ushort* dst) {
#pragma unroll
    for (int s = 0; s < 8; ++s)
      gload_lds16(srcp[s] + kofs, dst + s * 512);
  };
  auto compute = [&](const ushort* Ah, const ushort* Al,
                     const ushort* Bh, const ushort* Bl) {
    bf16x8 ah[4], al[4], bh[4], bl[4];
#pragma unroll
    for (int i = 0; i < 4; ++i) {
      int off = (wr * 4 + i) * 512 + lane * 8;
      ah[i] = *(const bf16x8*)&Ah[off];
      al[i] = *(const bf16x8*)&Al[off];
    }
#pragma unroll
    for (int j = 0; j < 4; ++j) {
      int off = (wc * 4 + j) * 512 + lane * 8;
      bh[j] = *(const bf16x8*)&Bh[off];
      bl[j] = *(const bf16x8*)&Bl[off];
    }
#pragma unroll
    for (int i = 0; i < 4; ++i)
#pragma unroll
      for (int j = 0; j < 4; ++j) {
        acc[i][j] = __builtin_amdgcn_mfma_f32_16x16x32_bf16(ah[i], bh[j], acc[i][j], 0, 0, 0);
        acc[i][j] = __builtin_amdgcn_mfma_f32_16x16x32_bf16(ah[i], bl[j], acc[i][j], 0, 0, 0);
        acc[i][j] = __builtin_amdgcn_mfma_f32_16x16x32_bf16(al[i], bh[j], acc[i][j], 0, 0, 0);
      }
  };

  // prologue: stage K-subtile 0 into buf0
  stage(kbase, dst0);
  DMA_DRAIN();
  __syncthreads();

#pragma unroll 1
  for (int tt = 0; tt < 8; ++tt) {
    const int t0 = tt * 2;
    // even step: compute buf0, stage buf1 with subtile t0+1 (always valid)
    stage(kbase + (t0 + 1) * 32, dst1);
    compute(ldsAh0, ldsAl0, ldsBh0, ldsBl0);
    DMA_DRAIN();
    __syncthreads();
    // odd step: compute buf1, stage buf0 with subtile t0+2 (if it exists)
    if (tt < 7) stage(kbase + (t0 + 2) * 32, dst0);
    compute(ldsAh1, ldsAl1, ldsBh1, ldsBl1);
    DMA_DRAIN();
    __syncthreads();
  }

  const int lr = (lane >> 4) << 2, lc = lane & 15;
  if (z == 16) {
    float* tp = kh ? tB : tA;
#pragma unroll
    for (int i = 0; i < 4; ++i) {
      int row = m0 + wr * 64 + i * 16 + lr;
#pragma unroll
      for (int j = 0; j < 4; ++j) {
        int col = n0 + wc * 64 + j * 16 + lc;
#pragma unroll
        for (int r = 0; r < 4; ++r)
          nt_store1f(&tp[(size_t)(row + r) * H_ + col], acc[i][j][r]);
      }
    }
  } else {
    float* hp = kh ? h1B : h1A;
#pragma unroll
    for (int i = 0; i < 4; ++i) {
      int pr[4]; bool ok[4];
#pragma unroll
      for (int r = 0; r < 4; ++r) {
        int li = m0 + wr * 64 + i * 16 + lr + r;
        ok[r] = li < n_e;
        pr[r] = pairlist[z * B_ + (ok[r] ? li : n_e - 1)];
      }
#pragma unroll
      for (int j = 0; j < 4; ++j) {
        int col = n0 + wc * 64 + j * 16 + lc;
#pragma unroll
        for (int r = 0; r < 4; ++r)
          if (ok[r]) nt_store1f(&hp[(size_t)pr[r] * HID_ + col], acc[i][j][r]);
      }
    }
  }
}

// ---------------------------------------------------------------------------
// Phase C: fused epilogue (unchanged from R8). One block per sample b.
// ---------------------------------------------------------------------------
__global__ __launch_bounds__(256) void epi_kernel(
    const float* __restrict__ tA, const float* __restrict__ tB,
    const float* __restrict__ bd,
    const float* __restrict__ Wo, const float* __restrict__ bo,
    const float* __restrict__ h1A, const float* __restrict__ h1B,
    const float* __restrict__ be1,
    const float* __restrict__ g1, const float* __restrict__ beta1,
    const int* __restrict__ topk_idx, const float* __restrict__ topk_prob,
    const float* __restrict__ Wcomb, const float* __restrict__ bcomb,
    const float* __restrict__ Wf1, const float* __restrict__ bf1,
    const float* __restrict__ gf, const float* __restrict__ betaf,
    const float* __restrict__ Wf2, const float* __restrict__ bf2,
    float* __restrict__ out) {
  const int b = blockIdx.x;
  const int tid = threadIdx.x;
  const int w = tid >> 6, lane = tid & 63;
  __shared__ float sCtr[4][3];
  __shared__ float sOl[4][3];

  const int pair = b * K_ + w;
  const int e = topk_idx[pair];
  const float prob = topk_prob[pair];
  const float* hrA = h1A + (size_t)pair * HID_;
  const float* hrB = h1B + (size_t)pair * HID_;
  const float* ber = be1 + (size_t)e * HID_;
  float x[4][4];
#pragma unroll
  for (int q = 0; q < 4; ++q) {
    const int d = q * 256 + lane * 4;
    fvec4 a = nt_load4f(&hrA[d]);
    fvec4 bq = nt_load4f(&hrB[d]);
    float4 be = *(const float4*)&ber[d];
    x[q][0] = a.x + bq.x + be.x; x[q][1] = a.y + bq.y + be.y;
    x[q][2] = a.z + bq.z + be.z; x[q][3] = a.w + bq.w + be.w;
  }
  float s = 0;
#pragma unroll
  for (int q = 0; q < 4; ++q) s += x[q][0] + x[q][1] + x[q][2] + x[q][3];
#pragma unroll
  for (int off = 32; off; off >>= 1) s += __shfl_down(s, off);
  const float mu = __shfl(s, 0) * (1.0f / HID_);
  float sq = 0;
#pragma unroll
  for (int q = 0; q < 4; ++q)
#pragma unroll
    for (int i = 0; i < 4; ++i) {
      float d = x[q][i] - mu;
      sq += d * d;
    }
#pragma unroll
  for (int off = 32; off; off >>= 1) sq += __shfl_down(sq, off);
  const float inv = 1.0f / sqrtf(__shfl(sq, 0) * (1.0f / HID_) + EPS_);
  float c0 = 0, c1 = 0, c2 = 0;
#pragma unroll
  for (int q = 0; q < 4; ++q) {
    const int d = q * 256 + lane * 4;
    float4 gg = *(const float4*)&g1[(size_t)e * HID_ + d];
    float4 bb = *(const float4*)&beta1[(size_t)e * HID_ + d];
    float gv[4] = {gg.x, gg.y, gg.z, gg.w};
    float bv[4] = {bb.x, bb.y, bb.z, bb.w};
#pragma unroll
    for (int i = 0; i < 4; ++i) {
      float v = (x[q][i] - mu) * inv * gv[i] + bv[i];
      v = 0.5f * v * (1.0f + erff(v * 0.70710678118654752440f));  // exact gelu
      const float* wc = &Wcomb[(size_t)(e * HID_ + d + i) * 3];
      c0 = fmaf(v, wc[0], c0); c1 = fmaf(v, wc[1], c1); c2 = fmaf(v, wc[2], c2);
    }
  }
  waveRed3(c0, c1, c2);
  if (lane == 0) {
    sCtr[w][0] = prob * (c0 + bcomb[e * 3 + 0]);
    sCtr[w][1] = prob * (c1 + bcomb[e * 3 + 1]);
    sCtr[w][2] = prob * (c2 + bcomb[e * 3 + 2]);
  }

  {
    const int h0 = w * 256 + lane * 4;
    fvec4 ta = nt_load4f(&tA[(size_t)b * H_ + h0]);
    fvec4 tb = nt_load4f(&tB[(size_t)b * H_ + h0]);
    float4 bdv = *(const float4*)&bd[h0];
    float tvv[4] = {tanhf(ta.x + tb.x + bdv.x), tanhf(ta.y + tb.y + bdv.y),
                    tanhf(ta.z + tb.z + bdv.z), tanhf(ta.w + tb.w + bdv.w)};
    float o0 = 0, o1 = 0, o2 = 0;
#pragma unroll
    for (int i = 0; i < 4; ++i) {
      const float* wo = &Wo[(size_t)(h0 + i) * 3];
      o0 = fmaf(tvv[i], wo[0], o0); o1 = fmaf(tvv[i], wo[1], o1); o2 = fmaf(tvv[i], wo[2], o2);
    }
    waveRed3(o0, o1, o2);
    if (lane == 0) { sOl[w][0] = o0; sOl[w][1] = o1; sOl[w][2] = o2; }
  }
  __syncthreads();

  if (tid == 0) {
    float comb[6];
#pragma unroll
    for (int c = 0; c < 3; ++c) {
      comb[c] = sOl[0][c] + sOl[1][c] + sOl[2][c] + sOl[3][c] + bo[c];
      comb[3 + c] = sCtr[0][c] + sCtr[1][c] + sCtr[2][c] + sCtr[3][c];
    }
    float z[3];
#pragma unroll
    for (int c = 0; c < 3; ++c) {
      float sv = bf1[c];
#pragma unroll
      for (int i = 0; i < 6; ++i) sv = fmaf(comb[i], Wf1[i * 3 + c], sv);
      z[c] = sv;
    }
    float mu3 = (z[0] + z[1] + z[2]) * (1.0f / 3.0f);
    float v0 = z[0] - mu3, v1 = z[1] - mu3, v2 = z[2] - mu3;
    float var = (v0 * v0 + v1 * v1 + v2 * v2) * (1.0f / 3.0f);
    float inv3 = 1.0f / sqrtf(var + EPS_);
    float r[3];
#pragma unroll
    for (int c = 0; c < 3; ++c) {
      float zz = (z[c] - mu3) * inv3 * gf[c] + betaf[c];
      r[c] = zz > 0.0f ? zz : 0.0f;
    }
#pragma unroll
    for (int c = 0; c < 3; ++c) {
      float sv = bf2[c];
#pragma unroll
      for (int i = 0; i < 3; ++i) sv = fmaf(r[i], Wf2[i * 3 + c], sv);
      out[b * 3 + c] = sv;
    }
  }
}

// ---------------------------------------------------------------------------
extern "C" void kernel_launch(void* const* d_in, const int* in_sizes, int n_in,
                              void* d_out, int out_size, void* d_ws, size_t ws_size,
                              hipStream_t stream) {
  const float* hs    = (const float*)d_in[0];
  const float* Wd    = (const float*)d_in[1];
  const float* bd    = (const float*)d_in[2];
  const float* Wo    = (const float*)d_in[3];
  const float* bo    = (const float*)d_in[4];
  const float* Wr    = (const float*)d_in[5];
  const float* br    = (const float*)d_in[6];
  const float* We1   = (const float*)d_in[7];
  const float* be1   = (const float*)d_in[8];
  const float* g1    = (const float*)d_in[9];
  const float* beta1 = (const float*)d_in[10];
  const float* We2   = (const float*)d_in[11];
  const float* be2   = (const float*)d_in[12];
  const float* Wp    = (const float*)d_in[13];
  const float* bp    = (const float*)d_in[14];
  const float* Wf1   = (const float*)d_in[15];
  const float* bf1   = (const float*)d_in[16];
  const float* gf    = (const float*)d_in[17];
  const float* betaf = (const float*)d_in[18];
  const float* Wf2   = (const float*)d_in[19];
  const float* bf2   = (const float*)d_in[20];
  float* out = (float*)d_out;

  char* w = (char*)d_ws;
  size_t off = 0;
  auto alloc = [&](size_t bytes) {
    void* p = w + off;
    off = (off + bytes + 255) & ~(size_t)255;
    return p;
  };
  ushort* m_hi   = (ushort*)alloc((size_t)B_ * H_ * 2);
  ushort* m_lo   = (ushort*)alloc((size_t)B_ * H_ * 2);
  ushort* cls_hi = (ushort*)alloc((size_t)B_ * H_ * 2);
  ushort* cls_lo = (ushort*)alloc((size_t)B_ * H_ * 2);
  ushort* wd_hi  = (ushort*)alloc((size_t)H_ * H_ * 2);
  ushort* wd_lo  = (ushort*)alloc((size_t)H_ * H_ * 2);
  ushort* we1_hi = (ushort*)alloc((size_t)E_ * H_ * HID_ * 2);
  ushort* we1_lo = (ushort*)alloc((size_t)E_ * H_ * HID_ * 2);
  float* ws_tA   = (float*)alloc((size_t)B_ * H_ * 4);
  float* ws_tB   = (float*)alloc((size_t)B_ * H_ * 4);
  float* ws_h1A  = (float*)alloc((size_t)B_ * K_ * HID_ * 4);
  float* ws_h1B  = (float*)alloc((size_t)B_ * K_ * HID_ * 4);
  float* ws_wc   = (float*)alloc((size_t)E_ * HID_ * 3 * 4);
  float* ws_bc   = (float*)alloc(E_ * 3 * 4);
  float* ws_prob = (float*)alloc(B_ * K_ * 4);
  int* ws_idx = (int*)alloc(B_ * K_ * 4);
  int* ws_cnt = (int*)alloc(E_ * 4);
  int* ws_pl  = (int*)alloc(E_ * B_ * 4);
  if (off > ws_size) return;

  hipMemsetAsync(ws_cnt, 0, E_ * sizeof(int), stream);

  prep_kernel<<<NB_PREP, 256, 0, stream>>>(hs, Wd, We1, We2, Wp, bp, Wr, br, be2,
                                           m_hi, m_lo, cls_hi, cls_lo, wd_hi, wd_lo,
                                           we1_hi, we1_lo, ws_wc, ws_bc,
                                           ws_idx, ws_prob, ws_cnt, ws_pl);
  gemm_mega<<<dim3(8, 16, 17), 256, 0, stream>>>(m_hi, m_lo, cls_hi, cls_lo,
                                                 wd_hi, wd_lo, we1_hi, we1_lo,
                                                 ws_cnt, ws_pl, ws_tA, ws_tB, ws_h1A, ws_h1B);
  epi_kernel<<<B_, 256, 0, stream>>>(ws_tA, ws_tB, bd, Wo, bo, ws_h1A, ws_h1B, be1,
                                     g1, beta1, ws_idx, ws_prob, ws_wc, ws_bc,
                                     Wf1, bf1, gf, betaf, Wf2, bf2, out);
}

// Round 11
// 275.192 us; speedup vs baseline: 1.1445x; 1.0376x over previous
//
#include <hip/hip_runtime.h>
#include <math.h>

#define B_ 1024
#define S_ 128
#define H_ 1024
#define E_ 16
#define HID_ 1024
#define K_ 4
#define C_ 3
#define EPS_ 1e-5f

// prep kernel segment offsets (block ranges)
#define NB_MEAN 1024
#define NB_WD 256
#define NB_WE1 4096
#define NB_WC 4096
#define NB_RT 256
#define NB_BC 4
#define OFF_WD (NB_MEAN)
#define OFF_WE1 (OFF_WD + NB_WD)
#define OFF_WC (OFF_WE1 + NB_WE1)
#define OFF_RT (OFF_WC + NB_WC)
#define OFF_BC (OFF_RT + NB_RT)
#define NB_PREP (OFF_BC + NB_BC)

typedef __attribute__((ext_vector_type(8))) __bf16 bf16x8;
typedef __attribute__((ext_vector_type(4))) float f32x4;
typedef __attribute__((ext_vector_type(4))) float fvec4;
typedef __attribute__((ext_vector_type(4))) unsigned short usvec4;

__device__ __forceinline__ ushort bf16_rn(float f) {
  unsigned u = __float_as_uint(f);
  u += 0x7FFF + ((u >> 16) & 1);
  return (ushort)(u >> 16);
}
__device__ __forceinline__ float bf16_to_f(ushort h) {
  return __uint_as_float(((unsigned)h) << 16);
}
__device__ __forceinline__ void split2(float f, ushort& h, ushort& l) {
  h = bf16_rn(f);
  l = bf16_rn(f - bf16_to_f(h));
}
__device__ __forceinline__ void gload_lds16(const void* g, void* l) {
  __builtin_amdgcn_global_load_lds((const __attribute__((address_space(1))) void*)g,
                                   (__attribute__((address_space(3))) void*)l, 16, 0, 0);
}
// Explicit LDS-DMA drain (rule #18: asm waitcnt + sched_barrier(0)).
#define DMA_DRAIN() do {                                  \
    asm volatile("s_waitcnt vmcnt(0)" ::: "memory");      \
    __builtin_amdgcn_sched_barrier(0);                    \
  } while (0)

// nontemporal shims — used ONLY for true stream-once data (hs reads, weight
// fp32 reads, split-K partial stores). Split outputs are re-read by the GEMM
// (~300 MB staging vs 76 MB unique) and must stay cacheable.
__device__ __forceinline__ fvec4 nt_load4f(const float* p) {
  return __builtin_nontemporal_load((const fvec4*)p);
}
__device__ __forceinline__ void st4us(ushort* p, ushort a, ushort b, ushort c, ushort d) {
  usvec4 v; v.x = a; v.y = b; v.z = c; v.w = d;
  *(usvec4*)p = v;
}
__device__ __forceinline__ void nt_store1f(float* p, float v) {
  __builtin_nontemporal_store(v, p);
}
__device__ __forceinline__ void waveRed3(float& s0, float& s1, float& s2) {
#pragma unroll
  for (int off = 32; off; off >>= 1) {
    s0 += __shfl_down(s0, off); s1 += __shfl_down(s1, off); s2 += __shfl_down(s2, off);
  }
}

// ---------------------------------------------------------------------------
// Phase A: prep mega-kernel. nt on hs/weight READS (stream-once); split
// outputs via normal cached stores (GEMM re-reads them from L2/L3).
// ---------------------------------------------------------------------------
__global__ __launch_bounds__(256) void prep_kernel(
    const float* __restrict__ hs,
    const float* __restrict__ Wd, const float* __restrict__ We1,
    const float* __restrict__ We2, const float* __restrict__ Wp, const float* __restrict__ bp,
    const float* __restrict__ Wr, const float* __restrict__ br,
    const float* __restrict__ be2,
    ushort* __restrict__ m_hi, ushort* __restrict__ m_lo,
    ushort* __restrict__ cls_hi, ushort* __restrict__ cls_lo,
    ushort* __restrict__ wd_hi, ushort* __restrict__ wd_lo,
    ushort* __restrict__ we1_hi, ushort* __restrict__ we1_lo,
    float* __restrict__ Wcomb, float* __restrict__ bcomb,
    int* __restrict__ topk_idx, float* __restrict__ topk_prob,
    int* __restrict__ counts, int* __restrict__ pairlist) {
  __shared__ float tbuf[64][65];
  const int blk = blockIdx.x;
  const int tid = threadIdx.x;

  if (blk < NB_MEAN) {
    int gid = blk * 256 + tid;
    int b = gid >> 8;
    int h4 = (gid & 255) << 2;
    const float* p = hs + (size_t)b * S_ * H_ + h4;
    fvec4 v0 = nt_load4f(p);
    float sx = v0.x, sy = v0.y, sz = v0.z, sw = v0.w;
#pragma unroll 8
    for (int s = 1; s < S_; ++s) {
      fvec4 v = nt_load4f(p + (size_t)s * H_);
      sx += v.x; sy += v.y; sz += v.z; sw += v.w;
    }
    const float inv = 1.0f / (float)S_;
    float mv[4] = {sx * inv, sy * inv, sz * inv, sw * inv};
    float cv[4] = {v0.x, v0.y, v0.z, v0.w};
    ushort mh[4], ml[4], ch[4], cl[4];
#pragma unroll
    for (int i = 0; i < 4; ++i) { split2(mv[i], mh[i], ml[i]); split2(cv[i], ch[i], cl[i]); }
    size_t o = (size_t)b * H_ + h4;
    st4us(&m_hi[o], mh[0], mh[1], mh[2], mh[3]);
    st4us(&m_lo[o], ml[0], ml[1], ml[2], ml[3]);
    st4us(&cls_hi[o], ch[0], ch[1], ch[2], ch[3]);
    st4us(&cls_lo[o], cl[0], cl[1], cl[2], cl[3]);
  } else if (blk < OFF_WC) {
    int t, zmat;
    const float* in;
    ushort *oh, *ol;
    if (blk < OFF_WE1) { t = blk - OFF_WD; zmat = 0; in = Wd; oh = wd_hi; ol = wd_lo; }
    else { int t2 = blk - OFF_WE1; zmat = t2 >> 8; t = t2 & 255; in = We1; oh = we1_hi; ol = we1_lo; }
    const int k0 = (t & 15) * 64, n0 = (t >> 4) * 64;
    const size_t mbase = (size_t)zmat * (1024 * 1024);
    const int c4 = (tid & 15) << 2;
    const int r0 = tid >> 4;
#pragma unroll
    for (int p = 0; p < 4; ++p) {
      int row = r0 + p * 16;
      fvec4 v = nt_load4f(&in[mbase + (size_t)(k0 + row) * 1024 + n0 + c4]);
      tbuf[row][c4] = v.x; tbuf[row][c4 + 1] = v.y; tbuf[row][c4 + 2] = v.z; tbuf[row][c4 + 3] = v.w;
    }
    __syncthreads();
    const int k4 = (tid & 15) << 2;
#pragma unroll
    for (int p = 0; p < 4; ++p) {
      int n = r0 + p * 16;
      ushort hh[4], ll[4];
#pragma unroll
      for (int i = 0; i < 4; ++i) split2(tbuf[k4 + i][n], hh[i], ll[i]);
      size_t o = mbase + (size_t)(n0 + n) * 1024 + k0 + k4;
      st4us(&oh[o], hh[0], hh[1], hh[2], hh[3]);
      st4us(&ol[o], ll[0], ll[1], ll[2], ll[3]);
    }
  } else if (blk < OFF_RT) {
    const int row = (blk - OFF_WC) * 4 + (tid >> 6);
    const int lane = tid & 63;
    const float* wr = We2 + (size_t)row * HID_;
    float s0 = 0, s1 = 0, s2 = 0;
    for (int f = lane; f < HID_; f += 64) {
      float v = wr[f];
      s0 = fmaf(v, Wp[f * 3 + 0], s0);
      s1 = fmaf(v, Wp[f * 3 + 1], s1);
      s2 = fmaf(v, Wp[f * 3 + 2], s2);
    }
    waveRed3(s0, s1, s2);
    if (lane == 0) {
      Wcomb[row * 3 + 0] = s0; Wcomb[row * 3 + 1] = s1; Wcomb[row * 3 + 2] = s2;
    }
  } else if (blk < OFF_BC) {
    const int lane = tid & 63;
    const int b = (blk - OFF_RT) * 4 + (tid >> 6);
    const float* cls = hs + (size_t)b * S_ * H_;
    const int e = lane & 15, part = lane >> 4;
    float sum = 0.0f;
    for (int i = part * 256; i < part * 256 + 256; ++i)
      sum = fmaf(cls[i], Wr[i * E_ + e], sum);
    sum += __shfl_down(sum, 32);
    sum += __shfl_down(sum, 16);
    float lg[E_];
#pragma unroll
    for (int i = 0; i < E_; ++i) lg[i] = __shfl(sum, i);
    if (lane == 0) {
      for (int i = 0; i < E_; ++i) lg[i] += br[i];
      int idx[K_]; float tv[K_];
      for (int k = 0; k < K_; ++k) {
        int bi = 0; float bv = -1e30f;
        for (int i = 0; i < E_; ++i) { if (lg[i] > bv) { bv = lg[i]; bi = i; } }
        idx[k] = bi; tv[k] = bv; lg[bi] = -1e30f;
      }
      float mx = tv[0], ssum = 0.0f, p[K_];
      for (int k = 0; k < K_; ++k) { p[k] = expf(tv[k] - mx); ssum += p[k]; }
      for (int k = 0; k < K_; ++k) {
        p[k] /= ssum;
        topk_idx[b * K_ + k] = idx[k];
        topk_prob[b * K_ + k] = p[k];
        int pos = atomicAdd(&counts[idx[k]], 1);
        pairlist[idx[k] * B_ + pos] = b * K_ + k;
      }
    }
  } else {
    const int e = (blk - OFF_BC) * 4 + (tid >> 6);
    const int lane = tid & 63;
    const float* wr = be2 + (size_t)e * HID_;
    float s0 = 0, s1 = 0, s2 = 0;
    for (int f = lane; f < HID_; f += 64) {
      float v = wr[f];
      s0 = fmaf(v, Wp[f * 3 + 0], s0);
      s1 = fmaf(v, Wp[f * 3 + 1], s1);
      s2 = fmaf(v, Wp[f * 3 + 2], s2);
    }
    waveRed3(s0, s1, s2);
    if (lane == 0) {
      bcomb[e * 3 + 0] = s0 + bp[0]; bcomb[e * 3 + 1] = s1 + bp[1]; bcomb[e * 3 + 2] = s2 + bp[2];
    }
  }
}

// ---------------------------------------------------------------------------
// Phase B: unified MFMA GEMM (R10 race-fixed dbuf, unchanged): 128x128 tile,
// SPLIT-K=2, BK=32, 2-phase static-named double-buffer, explicit DMA drain
// before every barrier. Raw split-K partials out via nontemporal stores.
// ---------------------------------------------------------------------------
__global__ __launch_bounds__(256) void gemm_mega(
    const ushort* __restrict__ m_hi, const ushort* __restrict__ m_lo,
    const ushort* __restrict__ cls_hi, const ushort* __restrict__ cls_lo,
    const ushort* __restrict__ wd_hi, const ushort* __restrict__ wd_lo,
    const ushort* __restrict__ we1_hi, const ushort* __restrict__ we1_lo,
    const int* __restrict__ counts, const int* __restrict__ pairlist,
    float* __restrict__ tA, float* __restrict__ tB,
    float* __restrict__ h1A, float* __restrict__ h1B) {
  __shared__ __align__(16) ushort ldsAh0[4096], ldsAl0[4096], ldsBh0[4096], ldsBl0[4096];
  __shared__ __align__(16) ushort ldsAh1[4096], ldsAl1[4096], ldsBh1[4096], ldsBl1[4096];
  const int z = blockIdx.z;
  const int tid = threadIdx.x;
  const int lane = tid & 63, w = tid >> 6;
  const int mt = blockIdx.y >> 1, kh = blockIdx.y & 1;
  const int m0 = mt * 128, n0 = blockIdx.x * 128;
  const int kbase = kh * 512;
  const ushort* srcp[8];
  ushort* dst0 = (w == 0) ? ldsAh0 : (w == 1) ? ldsAl0 : (w == 2) ? ldsBh0 : ldsBl0;
  ushort* dst1 = (w == 0) ? ldsAh1 : (w == 1) ? ldsAl1 : (w == 2) ? ldsBh1 : ldsBl1;
  int n_e;
  if (z == 16) {
    n_e = B_;
    const ushort* sbase = (w == 0) ? cls_hi : (w == 1) ? cls_lo : (w == 2) ? wd_hi : wd_lo;
    const int base0 = (w < 2) ? m0 : n0;
#pragma unroll
    for (int s = 0; s < 8; ++s) {
      int idx = base0 + s * 16 + (lane & 15);
      srcp[s] = sbase + (size_t)idx * H_ + ((lane >> 4) << 3);
    }
  } else {
    n_e = counts[z];
    if (m0 >= n_e) return;
    if (w < 2) {
      const ushort* sbase = (w == 0) ? m_hi : m_lo;
#pragma unroll
      for (int s = 0; s < 8; ++s) {
        int r = m0 + s * 16 + (lane & 15);
        if (r >= n_e) r = n_e - 1;
        int srow = pairlist[z * B_ + r] >> 2;
        srcp[s] = sbase + (size_t)srow * H_ + ((lane >> 4) << 3);
      }
    } else {
      const ushort* sbase = ((w == 2) ? we1_hi : we1_lo) + (size_t)z * H_ * HID_;
#pragma unroll
      for (int s = 0; s < 8; ++s) {
        int col = n0 + s * 16 + (lane & 15);
        srcp[s] = sbase + (size_t)col * H_ + ((lane >> 4) << 3);
      }
    }
  }
  const int wr = w >> 1, wc = w & 1;
  f32x4 acc[4][4] = {};

  auto stage = [&](int kofs, ushort* dst) {
#pragma unroll
    for (int s = 0; s < 8; ++s)
      gload_lds16(srcp[s] + kofs, dst + s * 512);
  };
  auto compute = [&](const ushort* Ah, const ushort* Al,
                     const ushort* Bh, const ushort* Bl) {
    bf16x8 ah[4], al[4], bh[4], bl[4];
#pragma unroll
    for (int i = 0; i < 4; ++i) {
      int off = (wr * 4 + i) * 512 + lane * 8;
      ah[i] = *(const bf16x8*)&Ah[off];
      al[i] = *(const bf16x8*)&Al[off];
    }
#pragma unroll
    for (int j = 0; j < 4; ++j) {
      int off = (wc * 4 + j) * 512 + lane * 8;
      bh[j] = *(const bf16x8*)&Bh[off];
      bl[j] = *(const bf16x8*)&Bl[off];
    }
#pragma unroll
    for (int i = 0; i < 4; ++i)
#pragma unroll
      for (int j = 0; j < 4; ++j) {
        acc[i][j] = __builtin_amdgcn_mfma_f32_16x16x32_bf16(ah[i], bh[j], acc[i][j], 0, 0, 0);
        acc[i][j] = __builtin_amdgcn_mfma_f32_16x16x32_bf16(ah[i], bl[j], acc[i][j], 0, 0, 0);
        acc[i][j] = __builtin_amdgcn_mfma_f32_16x16x32_bf16(al[i], bh[j], acc[i][j], 0, 0, 0);
      }
  };

  stage(kbase, dst0);
  DMA_DRAIN();
  __syncthreads();

#pragma unroll 1
  for (int tt = 0; tt < 8; ++tt) {
    const int t0 = tt * 2;
    stage(kbase + (t0 + 1) * 32, dst1);
    compute(ldsAh0, ldsAl0, ldsBh0, ldsBl0);
    DMA_DRAIN();
    __syncthreads();
    if (tt < 7) stage(kbase + (t0 + 2) * 32, dst0);
    compute(ldsAh1, ldsAl1, ldsBh1, ldsBl1);
    DMA_DRAIN();
    __syncthreads();
  }

  const int lr = (lane >> 4) << 2, lc = lane & 15;
  if (z == 16) {
    float* tp = kh ? tB : tA;
#pragma unroll
    for (int i = 0; i < 4; ++i) {
      int row = m0 + wr * 64 + i * 16 + lr;
#pragma unroll
      for (int j = 0; j < 4; ++j) {
        int col = n0 + wc * 64 + j * 16 + lc;
#pragma unroll
        for (int r = 0; r < 4; ++r)
          nt_store1f(&tp[(size_t)(row + r) * H_ + col], acc[i][j][r]);
      }
    }
  } else {
    float* hp = kh ? h1B : h1A;
#pragma unroll
    for (int i = 0; i < 4; ++i) {
      int pr[4]; bool ok[4];
#pragma unroll
      for (int r = 0; r < 4; ++r) {
        int li = m0 + wr * 64 + i * 16 + lr + r;
        ok[r] = li < n_e;
        pr[r] = pairlist[z * B_ + (ok[r] ? li : n_e - 1)];
      }
#pragma unroll
      for (int j = 0; j < 4; ++j) {
        int col = n0 + wc * 64 + j * 16 + lc;
#pragma unroll
        for (int r = 0; r < 4; ++r)
          if (ok[r]) nt_store1f(&hp[(size_t)pr[r] * HID_ + col], acc[i][j][r]);
      }
    }
  }
}

// ---------------------------------------------------------------------------
// Phase C: fused epilogue (unchanged). One block per sample b.
// ---------------------------------------------------------------------------
__global__ __launch_bounds__(256) void epi_kernel(
    const float* __restrict__ tA, const float* __restrict__ tB,
    const float* __restrict__ bd,
    const float* __restrict__ Wo, const float* __restrict__ bo,
    const float* __restrict__ h1A, const float* __restrict__ h1B,
    const float* __restrict__ be1,
    const float* __restrict__ g1, const float* __restrict__ beta1,
    const int* __restrict__ topk_idx, const float* __restrict__ topk_prob,
    const float* __restrict__ Wcomb, const float* __restrict__ bcomb,
    const float* __restrict__ Wf1, const float* __restrict__ bf1,
    const float* __restrict__ gf, const float* __restrict__ betaf,
    const float* __restrict__ Wf2, const float* __restrict__ bf2,
    float* __restrict__ out) {
  const int b = blockIdx.x;
  const int tid = threadIdx.x;
  const int w = tid >> 6, lane = tid & 63;
  __shared__ float sCtr[4][3];
  __shared__ float sOl[4][3];

  const int pair = b * K_ + w;
  const int e = topk_idx[pair];
  const float prob = topk_prob[pair];
  const float* hrA = h1A + (size_t)pair * HID_;
  const float* hrB = h1B + (size_t)pair * HID_;
  const float* ber = be1 + (size_t)e * HID_;
  float x[4][4];
#pragma unroll
  for (int q = 0; q < 4; ++q) {
    const int d = q * 256 + lane * 4;
    fvec4 a = nt_load4f(&hrA[d]);
    fvec4 bq = nt_load4f(&hrB[d]);
    float4 be = *(const float4*)&ber[d];
    x[q][0] = a.x + bq.x + be.x; x[q][1] = a.y + bq.y + be.y;
    x[q][2] = a.z + bq.z + be.z; x[q][3] = a.w + bq.w + be.w;
  }
  float s = 0;
#pragma unroll
  for (int q = 0; q < 4; ++q) s += x[q][0] + x[q][1] + x[q][2] + x[q][3];
#pragma unroll
  for (int off = 32; off; off >>= 1) s += __shfl_down(s, off);
  const float mu = __shfl(s, 0) * (1.0f / HID_);
  float sq = 0;
#pragma unroll
  for (int q = 0; q < 4; ++q)
#pragma unroll
    for (int i = 0; i < 4; ++i) {
      float d = x[q][i] - mu;
      sq += d * d;
    }
#pragma unroll
  for (int off = 32; off; off >>= 1) sq += __shfl_down(sq, off);
  const float inv = 1.0f / sqrtf(__shfl(sq, 0) * (1.0f / HID_) + EPS_);
  float c0 = 0, c1 = 0, c2 = 0;
#pragma unroll
  for (int q = 0; q < 4; ++q) {
    const int d = q * 256 + lane * 4;
    float4 gg = *(const float4*)&g1[(size_t)e * HID_ + d];
    float4 bb = *(const float4*)&beta1[(size_t)e * HID_ + d];
    float gv[4] = {gg.x, gg.y, gg.z, gg.w};
    float bv[4] = {bb.x, bb.y, bb.z, bb.w};
#pragma unroll
    for (int i = 0; i < 4; ++i) {
      float v = (x[q][i] - mu) * inv * gv[i] + bv[i];
      v = 0.5f * v * (1.0f + erff(v * 0.70710678118654752440f));  // exact gelu
      const float* wc = &Wcomb[(size_t)(e * HID_ + d + i) * 3];
      c0 = fmaf(v, wc[0], c0); c1 = fmaf(v, wc[1], c1); c2 = fmaf(v, wc[2], c2);
    }
  }
  waveRed3(c0, c1, c2);
  if (lane == 0) {
    sCtr[w][0] = prob * (c0 + bcomb[e * 3 + 0]);
    sCtr[w][1] = prob * (c1 + bcomb[e * 3 + 1]);
    sCtr[w][2] = prob * (c2 + bcomb[e * 3 + 2]);
  }

  {
    const int h0 = w * 256 + lane * 4;
    fvec4 ta = nt_load4f(&tA[(size_t)b * H_ + h0]);
    fvec4 tb = nt_load4f(&tB[(size_t)b * H_ + h0]);
    float4 bdv = *(const float4*)&bd[h0];
    float tvv[4] = {tanhf(ta.x + tb.x + bdv.x), tanhf(ta.y + tb.y + bdv.y),
                    tanhf(ta.z + tb.z + bdv.z), tanhf(ta.w + tb.w + bdv.w)};
    float o0 = 0, o1 = 0, o2 = 0;
#pragma unroll
    for (int i = 0; i < 4; ++i) {
      const float* wo = &Wo[(size_t)(h0 + i) * 3];
      o0 = fmaf(tvv[i], wo[0], o0); o1 = fmaf(tvv[i], wo[1], o1); o2 = fmaf(tvv[i], wo[2], o2);
    }
    waveRed3(o0, o1, o2);
    if (lane == 0) { sOl[w][0] = o0; sOl[w][1] = o1; sOl[w][2] = o2; }
  }
  __syncthreads();

  if (tid == 0) {
    float comb[6];
#pragma unroll
    for (int c = 0; c < 3; ++c) {
      comb[c] = sOl[0][c] + sOl[1][c] + sOl[2][c] + sOl[3][c] + bo[c];
      comb[3 + c] = sCtr[0][c] + sCtr[1][c] + sCtr[2][c] + sCtr[3][c];
    }
    float z[3];
#pragma unroll
    for (int c = 0; c < 3; ++c) {
      float sv = bf1[c];
#pragma unroll
      for (int i = 0; i < 6; ++i) sv = fmaf(comb[i], Wf1[i * 3 + c], sv);
      z[c] = sv;
    }
    float mu3 = (z[0] + z[1] + z[2]) * (1.0f / 3.0f);
    float v0 = z[0] - mu3, v1 = z[1] - mu3, v2 = z[2] - mu3;
    float var = (v0 * v0 + v1 * v1 + v2 * v2) * (1.0f / 3.0f);
    float inv3 = 1.0f / sqrtf(var + EPS_);
    float r[3];
#pragma unroll
    for (int c = 0; c < 3; ++c) {
      float zz = (z[c] - mu3) * inv3 * gf[c] + betaf[c];
      r[c] = zz > 0.0f ? zz : 0.0f;
    }
#pragma unroll
    for (int c = 0; c < 3; ++c) {
      float sv = bf2[c];
#pragma unroll
      for (int i = 0; i < 3; ++i) sv = fmaf(r[i], Wf2[i * 3 + c], sv);
      out[b * 3 + c] = sv;
    }
  }
}

// ---------------------------------------------------------------------------
extern "C" void kernel_launch(void* const* d_in, const int* in_sizes, int n_in,
                              void* d_out, int out_size, void* d_ws, size_t ws_size,
                              hipStream_t stream) {
  const float* hs    = (const float*)d_in[0];
  const float* Wd    = (const float*)d_in[1];
  const float* bd    = (const float*)d_in[2];
  const float* Wo    = (const float*)d_in[3];
  const float* bo    = (const float*)d_in[4];
  const float* Wr    = (const float*)d_in[5];
  const float* br    = (const float*)d_in[6];
  const float* We1   = (const float*)d_in[7];
  const float* be1   = (const float*)d_in[8];
  const float* g1    = (const float*)d_in[9];
  const float* beta1 = (const float*)d_in[10];
  const float* We2   = (const float*)d_in[11];
  const float* be2   = (const float*)d_in[12];
  const float* Wp    = (const float*)d_in[13];
  const float* bp    = (const float*)d_in[14];
  const float* Wf1   = (const float*)d_in[15];
  const float* bf1   = (const float*)d_in[16];
  const float* gf    = (const float*)d_in[17];
  const float* betaf = (const float*)d_in[18];
  const float* Wf2   = (const float*)d_in[19];
  const float* bf2   = (const float*)d_in[20];
  float* out = (float*)d_out;

  char* w = (char*)d_ws;
  size_t off = 0;
  auto alloc = [&](size_t bytes) {
    void* p = w + off;
    off = (off + bytes + 255) & ~(size_t)255;
    return p;
  };
  ushort* m_hi   = (ushort*)alloc((size_t)B_ * H_ * 2);
  ushort* m_lo   = (ushort*)alloc((size_t)B_ * H_ * 2);
  ushort* cls_hi = (ushort*)alloc((size_t)B_ * H_ * 2);
  ushort* cls_lo = (ushort*)alloc((size_t)B_ * H_ * 2);
  ushort* wd_hi  = (ushort*)alloc((size_t)H_ * H_ * 2);
  ushort* wd_lo  = (ushort*)alloc((size_t)H_ * H_ * 2);
  ushort* we1_hi = (ushort*)alloc((size_t)E_ * H_ * HID_ * 2);
  ushort* we1_lo = (ushort*)alloc((size_t)E_ * H_ * HID_ * 2);
  float* ws_tA   = (float*)alloc((size_t)B_ * H_ * 4);
  float* ws_tB   = (float*)alloc((size_t)B_ * H_ * 4);
  float* ws_h1A  = (float*)alloc((size_t)B_ * K_ * HID_ * 4);
  float* ws_h1B  = (float*)alloc((size_t)B_ * K_ * HID_ * 4);
  float* ws_wc   = (float*)alloc((size_t)E_ * HID_ * 3 * 4);
  float* ws_bc   = (float*)alloc(E_ * 3 * 4);
  float* ws_prob = (float*)alloc(B_ * K_ * 4);
  int* ws_idx = (int*)alloc(B_ * K_ * 4);
  int* ws_cnt = (int*)alloc(E_ * 4);
  int* ws_pl  = (int*)alloc(E_ * B_ * 4);
  if (off > ws_size) return;

  hipMemsetAsync(ws_cnt, 0, E_ * sizeof(int), stream);

  prep_kernel<<<NB_PREP, 256, 0, stream>>>(hs, Wd, We1, We2, Wp, bp, Wr, br, be2,
                                           m_hi, m_lo, cls_hi, cls_lo, wd_hi, wd_lo,
                                           we1_hi, we1_lo, ws_wc, ws_bc,
                                           ws_idx, ws_prob, ws_cnt, ws_pl);
  gemm_mega<<<dim3(8, 16, 17), 256, 0, stream>>>(m_hi, m_lo, cls_hi, cls_lo,
                                                 wd_hi, wd_lo, we1_hi, we1_lo,
                                                 ws_cnt, ws_pl, ws_tA, ws_tB, ws_h1A, ws_h1B);
  epi_kernel<<<B_, 256, 0, stream>>>(ws_tA, ws_tB, bd, Wo, bo, ws_h1A, ws_h1B, be1,
                                     g1, beta1, ws_idx, ws_prob, ws_wc, ws_bc,
                                     Wf1, bf1, gf, betaf, Wf2, bf2, out);
}